// Round 11
// baseline (282.684 us; speedup 1.0000x reference)
//
#include <hip/hip_runtime.h>
#include <hip/hip_bf16.h>
#include <math.h>

#define N_NODES 24576
#define NPV 8192
#define E_EDGES 393216
#define R_REL 6
#define B_BASES 8
#define HEADS 4
#define NEG_SLOPE 0.2f
#define NX (N_NODES * 128)
#define NK (N_NODES * R_REL)
#define SCAN_BLOCKS (NK / 256)  // 576

typedef unsigned short ushort_t;
using short8 = __attribute__((ext_vector_type(8))) short;
using f32x4 = __attribute__((ext_vector_type(4))) float;

__device__ __forceinline__ float lrelu(float x) { return x >= 0.f ? x : NEG_SLOPE * x; }
__device__ __forceinline__ float b2f(ushort_t u) {
  unsigned int v = ((unsigned int)u) << 16;
  float f;
  __builtin_memcpy(&f, &v, 4);
  return f;
}
__device__ __forceinline__ ushort_t f2b(float f) {
  __hip_bfloat16 h = __float2bfloat16(f);
  ushort_t u;
  __builtin_memcpy(&u, &h, 2);
  return u;
}

// ---------------------------------------------------------------------------
// gemm_proj_split: split-K projection, NO atomics, BM=32 high-TLP variant.
// grid (NPV/32, 9): z -> (view, K-chunk). 2304 blocks, 20KB LDS -> ~8
// blocks/CU so HBM latency is hidden by wave TLP (r10 lesson: ILP pipeline
// cost occupancy and netted zero). Partial f32 tiles to Ppart[z].
// ---------------------------------------------------------------------------
__global__ __launch_bounds__(256) void gemm_proj_split(
    const float* __restrict__ x0, const float* __restrict__ x1,
    const float* __restrict__ x2, const float* __restrict__ w0,
    const float* __restrict__ w1, const float* __restrict__ w2,
    float* __restrict__ Ppart) {
  __shared__ __align__(16) ushort_t As[32 * 64];
  __shared__ __align__(16) ushort_t Ws[128 * 64];
  const int z = blockIdx.y;
  const float* A;
  const float* W;
  int K, kstart, ksteps;
  if (z < 4)      { A = x0; W = w0; K = 2000; kstart = z * 512;       ksteps = 8; }
  else if (z < 7) { A = x1; W = w1; K = 1500; kstart = (z - 4) * 512; ksteps = 8; }
  else            { A = x2; W = w2; K = 500;  kstart = (z - 7) * 256; ksteps = 4; }
  const int tid = threadIdx.x;
  const int wave = tid >> 6, lane = tid & 63;
  const int m0 = blockIdx.x * 32;
  const int wrow = (wave & 1) * 16;   // wave's 16-row strip within 32-row tile
  const int wcol = (wave >> 1) * 64;  // wave's 64-col strip

  f32x4 acc[4];
#pragma unroll
  for (int n = 0; n < 4; ++n) acc[n] = (f32x4){0.f, 0.f, 0.f, 0.f};

  for (int step = 0; step < ksteps; ++step) {
    const int k0 = kstart + (step << 6);
    __syncthreads();
    // stage A tile (32 rows x 64 k): 1 chunk/thread, XOR-swizzled source
    {
      int row = tid >> 3, ch = tid & 7;
      int gk = k0 + ((ch ^ (row & 7)) << 3);
      const float* gp = A + (long)(m0 + row) * K + gk;
      short8 o;
      if (gk + 8 <= K) {
        float4 a = *reinterpret_cast<const float4*>(gp);
        float4 b = *reinterpret_cast<const float4*>(gp + 4);
        o[0] = (short)f2b(a.x); o[1] = (short)f2b(a.y);
        o[2] = (short)f2b(a.z); o[3] = (short)f2b(a.w);
        o[4] = (short)f2b(b.x); o[5] = (short)f2b(b.y);
        o[6] = (short)f2b(b.z); o[7] = (short)f2b(b.w);
      } else {
#pragma unroll
        for (int j = 0; j < 8; ++j)
          o[j] = (gk + j < K) ? (short)f2b(gp[j]) : (short)0;
      }
      *reinterpret_cast<short8*>(As + tid * 8) = o;
    }
    // stage W tile (128 rows x 64 k): 4 chunks/thread
#pragma unroll
    for (int q = 0; q < 4; ++q) {
      int s = q * 256 + tid;
      int row = s >> 3, ch = s & 7;
      int gk = k0 + ((ch ^ (row & 7)) << 3);
      const float* gp = W + (long)row * K + gk;
      short8 o;
      if (gk + 8 <= K) {
        float4 a = *reinterpret_cast<const float4*>(gp);
        float4 b = *reinterpret_cast<const float4*>(gp + 4);
        o[0] = (short)f2b(a.x); o[1] = (short)f2b(a.y);
        o[2] = (short)f2b(a.z); o[3] = (short)f2b(a.w);
        o[4] = (short)f2b(b.x); o[5] = (short)f2b(b.y);
        o[6] = (short)f2b(b.z); o[7] = (short)f2b(b.w);
      } else {
#pragma unroll
        for (int j = 0; j < 8; ++j)
          o[j] = (gk + j < K) ? (short)f2b(gp[j]) : (short)0;
      }
      *reinterpret_cast<short8*>(Ws + s * 8) = o;
    }
    __syncthreads();
#pragma unroll
    for (int kk = 0; kk < 2; ++kk) {
      const int arow = wrow + (lane & 15);
      const int ach = (kk * 4 + (lane >> 4)) ^ (arow & 7);
      short8 afrag = *reinterpret_cast<const short8*>(As + arow * 64 + ach * 8);
#pragma unroll
      for (int n = 0; n < 4; ++n) {
        const int brow = wcol + n * 16 + (lane & 15);
        const int bch = (kk * 4 + (lane >> 4)) ^ (brow & 7);
        short8 bfrag = *reinterpret_cast<const short8*>(Ws + brow * 64 + bch * 8);
        acc[n] = __builtin_amdgcn_mfma_f32_16x16x32_bf16(afrag, bfrag, acc[n], 0, 0, 0);
      }
    }
  }
  const int rbase = m0 + wrow + (lane >> 4) * 4;
  const int cb = lane & 15;
  float* out = Ppart + (long)z * NPV * 128;
#pragma unroll
  for (int n = 0; n < 4; ++n) {
    int col = wcol + n * 16 + cb;
#pragma unroll
    for (int r = 0; r < 4; ++r)
      out[(long)(rbase + r) * 128 + col] = acc[n][r];
  }
}

// proj_reduce: xb[n, c] = bf16(relu(sum_z Ppart[z][m, c] + bias_v[c]))
__global__ __launch_bounds__(256) void proj_reduce(
    const float* __restrict__ Ppart, const float* __restrict__ b0,
    const float* __restrict__ b1, const float* __restrict__ b2,
    ushort_t* __restrict__ xb) {
  int t = blockIdx.x * blockDim.x + threadIdx.x;
  if (t >= N_NODES * 16) return;
  int n = t >> 4, c0 = (t & 15) * 8;
  int v = n >> 13, m = n & (NPV - 1);
  int zb, zc;
  const float* bias;
  if (v == 0) { zb = 0; zc = 4; bias = b0; }
  else if (v == 1) { zb = 4; zc = 3; bias = b1; }
  else { zb = 7; zc = 2; bias = b2; }
  float s[8];
#pragma unroll
  for (int j = 0; j < 8; ++j) s[j] = bias[c0 + j];
  for (int zz = 0; zz < zc; ++zz) {
    const float* p = Ppart + ((long)(zb + zz) * NPV + m) * 128 + c0;
    float4 a = *reinterpret_cast<const float4*>(p);
    float4 b = *reinterpret_cast<const float4*>(p + 4);
    s[0] += a.x; s[1] += a.y; s[2] += a.z; s[3] += a.w;
    s[4] += b.x; s[5] += b.y; s[6] += b.z; s[7] += b.w;
  }
  short8 o;
#pragma unroll
  for (int j = 0; j < 8; ++j) {
    float vv = s[j] > 0.f ? s[j] : 0.f;
    o[j] = (short)f2b(vv);
  }
  *reinterpret_cast<short8*>(xb + (long)n * 128 + c0) = o;
}

// ---------------------------------------------------------------------------
// xw GEMM: xwb[r][M,128] = bf16(xb[M,128] @ w_r[128,128]^T), plus fused
// attention tables ai/aj = (xb@w_r) @ q / @ k from the f32 accumulators.
// ---------------------------------------------------------------------------
template <bool SPLIT, bool TABLES>
__global__ __launch_bounds__(256) void mfma_gemm_nt(
    const ushort_t* __restrict__ A, const ushort_t* __restrict__ W,
    float* __restrict__ Cacc, ushort_t* __restrict__ Cb,
    int Kp, int kChunk, long strideW, long strideCz,
    const float* __restrict__ qt, const float* __restrict__ kt,
    float* __restrict__ ai, float* __restrict__ aj) {
  __shared__ __align__(16) ushort_t As[64 * 64];
  __shared__ __align__(16) ushort_t Ws[128 * 64];
  const int tid = threadIdx.x;
  const int wave = tid >> 6, lane = tid & 63;
  const int m0 = blockIdx.x * 64;
  const int kbase = blockIdx.y * kChunk;
  const ushort_t* Wz = W + (long)blockIdx.z * strideW;

  f32x4 acc[8];
#pragma unroll
  for (int n = 0; n < 8; ++n) acc[n] = (f32x4){0.f, 0.f, 0.f, 0.f};

  for (int k0 = kbase; k0 < kbase + kChunk; k0 += 64) {
    __syncthreads();
#pragma unroll
    for (int q = 0; q < 2; ++q) {
      int s = q * 256 + tid;
      int row = s >> 3, ch = s & 7;
      int sch = ch ^ (row & 7);
      const ushort_t* g = A + (long)(m0 + row) * Kp + k0 + sch * 8;
      __builtin_amdgcn_global_load_lds(
          (const __attribute__((address_space(1))) unsigned int*)g,
          (__attribute__((address_space(3))) unsigned int*)(As + s * 8), 16, 0, 0);
    }
#pragma unroll
    for (int q = 0; q < 4; ++q) {
      int s = q * 256 + tid;
      int row = s >> 3, ch = s & 7;
      int sch = ch ^ (row & 7);
      const ushort_t* g = Wz + (long)row * Kp + k0 + sch * 8;
      __builtin_amdgcn_global_load_lds(
          (const __attribute__((address_space(1))) unsigned int*)g,
          (__attribute__((address_space(3))) unsigned int*)(Ws + s * 8), 16, 0, 0);
    }
    __syncthreads();
#pragma unroll
    for (int kk = 0; kk < 2; ++kk) {
      const int arow = wave * 16 + (lane & 15);
      const int ach = (kk * 4 + (lane >> 4)) ^ (arow & 7);
      short8 afrag = *reinterpret_cast<const short8*>(As + arow * 64 + ach * 8);
#pragma unroll
      for (int n = 0; n < 8; ++n) {
        const int brow = n * 16 + (lane & 15);
        const int bch = (kk * 4 + (lane >> 4)) ^ (brow & 7);
        short8 bfrag = *reinterpret_cast<const short8*>(Ws + brow * 64 + bch * 8);
        acc[n] = __builtin_amdgcn_mfma_f32_16x16x32_bf16(afrag, bfrag, acc[n], 0, 0, 0);
      }
    }
  }
  const int rbase = m0 + wave * 16 + (lane >> 4) * 4;
  const int cb = lane & 15;
  if (SPLIT) {
#pragma unroll
    for (int n = 0; n < 8; ++n) {
      int col = n * 16 + cb;
#pragma unroll
      for (int r = 0; r < 4; ++r)
        atomicAdd(&Cacc[(long)(rbase + r) * 128 + col], acc[n][r]);
    }
  } else {
    ushort_t* Cz = Cb + (long)blockIdx.z * strideCz;
#pragma unroll
    for (int n = 0; n < 8; ++n) {
      int col = n * 16 + cb;
#pragma unroll
      for (int r = 0; r < 4; ++r)
        Cz[(long)(rbase + r) * 128 + col] = f2b(acc[n][r]);
    }
  }
  if (TABLES) {
    float aq[4][4], ak[4][4];
#pragma unroll
    for (int r = 0; r < 4; ++r)
#pragma unroll
      for (int h = 0; h < 4; ++h) { aq[r][h] = 0.f; ak[r][h] = 0.f; }
#pragma unroll
    for (int n = 0; n < 8; ++n) {
      int col = n * 16 + cb;
      float4 qv = *reinterpret_cast<const float4*>(qt + (long)col * 4);
      float4 kv = *reinterpret_cast<const float4*>(kt + (long)col * 4);
#pragma unroll
      for (int r = 0; r < 4; ++r) {
        float x = acc[n][r];
        aq[r][0] += x * qv.x; aq[r][1] += x * qv.y;
        aq[r][2] += x * qv.z; aq[r][3] += x * qv.w;
        ak[r][0] += x * kv.x; ak[r][1] += x * kv.y;
        ak[r][2] += x * kv.z; ak[r][3] += x * kv.w;
      }
    }
#pragma unroll
    for (int mk = 1; mk < 16; mk <<= 1) {
#pragma unroll
      for (int r = 0; r < 4; ++r)
#pragma unroll
        for (int h = 0; h < 4; ++h) {
          aq[r][h] += __shfl_xor(aq[r][h], mk);
          ak[r][h] += __shfl_xor(ak[r][h], mk);
        }
    }
    int rr = cb >> 2, hh = cb & 3;
    long row = (long)blockIdx.z * N_NODES + rbase + rr;
    ai[row * 4 + hh] = aq[rr][hh];
    aj[row * 4 + hh] = ak[rr][hh];
  }
}

// ---------------------------------------------------------------------------
__global__ void fill_f32(float* __restrict__ p, long n, float v) {
  long i = blockIdx.x * (long)blockDim.x + threadIdx.x;
  long stride = (long)gridDim.x * blockDim.x;
  for (; i < n; i += stride) p[i] = v;
}

// wTb[r,o,i] = bf16( sum_b comp[r,b] * basis[b,i,o] )
__global__ void compute_wT_b(const float* __restrict__ comp,
                             const float* __restrict__ basis,
                             ushort_t* __restrict__ wTb) {
  int idx = blockIdx.x * blockDim.x + threadIdx.x;
  if (idx >= R_REL * 128 * 128) return;
  int r = idx >> 14;
  int rem = idx & 16383;
  int o = rem >> 7;
  int i = rem & 127;
  float s = 0.f;
#pragma unroll
  for (int b = 0; b < B_BASES; ++b)
    s += comp[r * B_BASES + b] * basis[((b << 7) + i) * 128 + o];
  wTb[((long)(r << 7) + o) * 128 + i] = f2b(s);
}

// ---------------------------------------------------------------------------
// CSR build keyed by (dst*6 + rel): count -> hierarchical scan -> scatter.
// ---------------------------------------------------------------------------
__global__ void count_key(const int* __restrict__ dst, const int* __restrict__ et,
                          int* __restrict__ cnt, int E) {
  int e = blockIdx.x * blockDim.x + threadIdx.x;
  if (e < E) atomicAdd(&cnt[dst[e] * R_REL + et[e]], 1);
}

__global__ __launch_bounds__(256) void scan_block(const int* __restrict__ cnt,
                                                  int* __restrict__ start,
                                                  int* __restrict__ blockSums) {
  __shared__ int sm[256];
  const int t = threadIdx.x;
  const int i = blockIdx.x * 256 + t;
  int v = cnt[i];
  sm[t] = v;
  __syncthreads();
  for (int off = 1; off < 256; off <<= 1) {
    int u = (t >= off) ? sm[t - off] : 0;
    __syncthreads();
    sm[t] += u;
    __syncthreads();
  }
  start[i] = sm[t] - v;  // exclusive
  if (t == 255) blockSums[blockIdx.x] = sm[255];
}

__global__ __launch_bounds__(SCAN_BLOCKS) void scan_sums(int* __restrict__ blockSums) {
  __shared__ int sm[SCAN_BLOCKS];
  const int t = threadIdx.x;
  int v = blockSums[t];
  sm[t] = v;
  __syncthreads();
  for (int off = 1; off < SCAN_BLOCKS; off <<= 1) {
    int u = (t >= off) ? sm[t - off] : 0;
    __syncthreads();
    sm[t] += u;
    __syncthreads();
  }
  blockSums[t] = sm[t] - v;  // exclusive
}

__global__ __launch_bounds__(256) void add_offsets(int* __restrict__ start,
                                                   const int* __restrict__ blockSums) {
  int i = blockIdx.x * 256 + threadIdx.x;
  start[i] += blockSums[blockIdx.x];
  if (i == 0) start[NK] = E_EDGES;
}

__global__ void scatter_edges(const int* __restrict__ src, const int* __restrict__ dst,
                              const int* __restrict__ et, const int* __restrict__ start,
                              int* __restrict__ cursor, int* __restrict__ recs, int E) {
  int e = blockIdx.x * blockDim.x + threadIdx.x;
  if (e >= E) return;
  int key = dst[e] * R_REL + et[e];
  int pos = start[key] + atomicAdd(&cursor[key], 1);
  recs[pos] = src[e] | (et[e] << 16);
}

// ---------------------------------------------------------------------------
// seg_softmax: one thread per (dst,rel) segment -> per-edge coef[h*E + pos].
// ---------------------------------------------------------------------------
__global__ __launch_bounds__(256) void seg_softmax(
    const int* __restrict__ rstart, const int* __restrict__ recs,
    const float* __restrict__ ai, const float* __restrict__ aj,
    float* __restrict__ coef) {
  int seg = blockIdx.x * blockDim.x + threadIdx.x;
  if (seg >= NK) return;
  int p0 = rstart[seg], p1 = rstart[seg + 1];
  if (p0 == p1) return;
  int d = seg / R_REL, r = seg - d * R_REL;
  float4 av = *reinterpret_cast<const float4*>(ai + ((long)r * N_NODES + d) * 4);
  float degf = (float)(rstart[(d + 1) * R_REL] - rstart[d * R_REL]);
  float m[4] = {-INFINITY, -INFINITY, -INFINITY, -INFINITY};
  float sum[4] = {0.f, 0.f, 0.f, 0.f};
  for (int p = p0; p < p1; ++p) {
    int s = recs[p] & 0xFFFF;
    float4 bv = *reinterpret_cast<const float4*>(aj + ((long)r * N_NODES + s) * 4);
    float al[4] = {lrelu(av.x + bv.x), lrelu(av.y + bv.y),
                   lrelu(av.z + bv.z), lrelu(av.w + bv.w)};
#pragma unroll
    for (int h = 0; h < 4; ++h) {
      float nm = fmaxf(m[h], al[h]);
      sum[h] = sum[h] * __expf(m[h] - nm) + __expf(al[h] - nm);
      m[h] = nm;
    }
  }
  float rs[4];
#pragma unroll
  for (int h = 0; h < 4; ++h) rs[h] = degf / (sum[h] + 1e-16f);
  for (int p = p0; p < p1; ++p) {
    int s = recs[p] & 0xFFFF;
    float4 bv = *reinterpret_cast<const float4*>(aj + ((long)r * N_NODES + s) * 4);
    float al[4] = {lrelu(av.x + bv.x), lrelu(av.y + bv.y),
                   lrelu(av.z + bv.z), lrelu(av.w + bv.w)};
#pragma unroll
    for (int h = 0; h < 4; ++h)
      coef[(long)h * E_EDGES + p] = __expf(al[h] - m[h]) * rs[h];
  }
}

// ---------------------------------------------------------------------------
// fused_agg: one wave per dst node; pure gather-accumulate over xwb.
// ---------------------------------------------------------------------------
__global__ __launch_bounds__(256) void fused_agg(
    const int* __restrict__ rstart, const int* __restrict__ recs,
    const float* __restrict__ coef, const ushort_t* __restrict__ xwb,
    ushort_t* __restrict__ xb_out, float* __restrict__ fout) {
  const int wave = threadIdx.x >> 6, lane = threadIdx.x & 63;
  const int d = blockIdx.x * 4 + wave;
  const int s0 = rstart[d * R_REL], s1 = rstart[(d + 1) * R_REL];
  const float* cfp = coef + (long)(lane >> 4) * E_EDGES;
  float acc0 = 0.f, acc1 = 0.f;
#pragma unroll 4
  for (int pos = s0; pos < s1; ++pos) {
    int rec = recs[pos];
    float cf = cfp[pos];
    int s = rec & 0xFFFF, r = rec >> 16;
    unsigned int pk = *reinterpret_cast<const unsigned int*>(
        xwb + (((long)r * N_NODES + s) << 7) + 2 * lane);
    acc0 += cf * b2f((ushort_t)(pk & 0xFFFF));
    acc1 += cf * b2f((ushort_t)(pk >> 16));
  }
  if (xb_out) {
    unsigned int po = ((unsigned int)f2b(acc1) << 16) | (unsigned int)f2b(acc0);
    *reinterpret_cast<unsigned int*>(xb_out + ((long)d << 7) + 2 * lane) = po;
  }
  if (fout) {
    *reinterpret_cast<float2*>(fout + ((long)d << 7) + 2 * lane) =
        make_float2(acc0, acc1);
  }
}

__global__ void final_linear(const float* __restrict__ x, const float* __restrict__ Wc,
                             const float* __restrict__ bc, float* __restrict__ out) {
  __shared__ float wcs[4 * 384];
  for (int t = threadIdx.x; t < 4 * 384; t += blockDim.x) wcs[t] = Wc[t];
  __syncthreads();
  int i = blockIdx.x * blockDim.x + threadIdx.x;
  if (i >= NPV) return;
  float acc[4] = {0.f, 0.f, 0.f, 0.f};
  for (int v = 0; v < 3; ++v) {
    const float* xr = x + ((long)v * NPV + i) * 128;
    for (int c = 0; c < 128; c += 4) {
      float4 xv = *reinterpret_cast<const float4*>(xr + c);
#pragma unroll
      for (int l = 0; l < 4; ++l) {
        const float* w = wcs + l * 384 + v * 128 + c;
        acc[l] += xv.x * w[0] + xv.y * w[1] + xv.z * w[2] + xv.w * w[3];
      }
    }
  }
#pragma unroll
  for (int l = 0; l < 4; ++l) out[(long)i * 4 + l] = acc[l] + bc[l];
}

// ---------------------------------------------------------------------------
static void run_layer(const ushort_t* xb_in, ushort_t* xb_out, float* fout,
                      const float* basis, const float* comp, const float* q,
                      const float* k, ushort_t* xwb, ushort_t* wTb, float* ai,
                      float* aj, float* coef, const int* rstart, const int* recs,
                      hipStream_t stream) {
  compute_wT_b<<<(R_REL * 128 * 128 + 255) / 256, 256, 0, stream>>>(comp, basis, wTb);
  mfma_gemm_nt<false, true><<<dim3(N_NODES / 64, 1, R_REL), 256, 0, stream>>>(
      xb_in, wTb, nullptr, xwb, 128, 128, 128 * 128, (long)N_NODES * 128,
      q, k, ai, aj);
  seg_softmax<<<(NK + 255) / 256, 256, 0, stream>>>(rstart, recs, ai, aj, coef);
  fused_agg<<<N_NODES / 4, 256, 0, stream>>>(rstart, recs, coef, xwb, xb_out, fout);
}

extern "C" void kernel_launch(void* const* d_in, const int* in_sizes, int n_in,
                              void* d_out, int out_size, void* d_ws, size_t ws_size,
                              hipStream_t stream) {
  const float* x0 = (const float*)d_in[0];
  const float* x1 = (const float*)d_in[1];
  const float* x2 = (const float*)d_in[2];
  const int* edge_index = (const int*)d_in[3];
  const int* edge_type = (const int*)d_in[4];
  const float* Wp0 = (const float*)d_in[5];
  const float* bp0 = (const float*)d_in[6];
  const float* Wp1 = (const float*)d_in[7];
  const float* bp1 = (const float*)d_in[8];
  const float* Wp2 = (const float*)d_in[9];
  const float* bp2 = (const float*)d_in[10];
  const float* basis0 = (const float*)d_in[11];
  const float* comp0 = (const float*)d_in[12];
  const float* q0 = (const float*)d_in[13];
  const float* k0 = (const float*)d_in[14];
  const float* basis1 = (const float*)d_in[15];
  const float* comp1 = (const float*)d_in[16];
  const float* q1 = (const float*)d_in[17];
  const float* k1 = (const float*)d_in[18];
  const float* Wc = (const float*)d_in[19];
  const float* bc = (const float*)d_in[20];

  const int* src = edge_index;
  const int* dst = edge_index + E_EDGES;

  // ---- workspace layout ----
  char* w = (char*)d_ws;
  auto alloc = [&](long bytes) {
    char* p = w;
    w += (bytes + 255) & ~255L;
    return p;
  };
  ushort_t* xbA  = (ushort_t*)alloc((long)NX * 2);
  ushort_t* xbB  = (ushort_t*)alloc((long)NX * 2);
  ushort_t* xwb  = (ushort_t*)alloc(9L * NPV * 128 * 4);  // aliased: Ppart (f32) then xwb (bf16)
  ushort_t* wTb  = (ushort_t*)alloc((long)R_REL * 128 * 128 * 2);
  float* Cacc    = (float*)alloc((long)NX * 4);
  float* ai      = (float*)alloc((long)R_REL * N_NODES * 4 * 4);
  float* aj      = (float*)alloc((long)R_REL * N_NODES * 4 * 4);
  float* coef    = (float*)alloc((long)HEADS * E_EDGES * 4);
  int* cnt       = (int*)alloc((long)NK * 4);
  int* cursor    = (int*)alloc((long)NK * 4);
  int* rstart    = (int*)alloc((long)(NK + 1) * 4);
  int* recs      = (int*)alloc((long)E_EDGES * 4);
  int* blockSums = (int*)alloc((long)SCAN_BLOCKS * 4);
  float* Ppart   = (float*)xwb;  // alias: projection partials die before xwb is written

  // ---- projections: high-TLP split-K (no atomics) -> partials -> reduce
  gemm_proj_split<<<dim3(NPV / 32, 9), 256, 0, stream>>>(
      x0, x1, x2, Wp0, Wp1, Wp2, Ppart);
  proj_reduce<<<(N_NODES * 16 + 255) / 256, 256, 0, stream>>>(
      Ppart, bp0, bp1, bp2, xbA);

  // ---- CSR build keyed by (dst,rel) (once; shared by both layers)
  fill_f32<<<96, 256, 0, stream>>>((float*)cnt, 2L * NK, 0.f);  // cnt+cursor adjacent
  count_key<<<E_EDGES / 256, 256, 0, stream>>>(dst, edge_type, cnt, E_EDGES);
  scan_block<<<SCAN_BLOCKS, 256, 0, stream>>>(cnt, rstart, blockSums);
  scan_sums<<<1, SCAN_BLOCKS, 0, stream>>>(blockSums);
  add_offsets<<<SCAN_BLOCKS, 256, 0, stream>>>(rstart, blockSums);
  scatter_edges<<<E_EDGES / 256, 256, 0, stream>>>(src, dst, edge_type, rstart,
                                                   cursor, recs, E_EDGES);

  // ---- layer 0: xbA -> xbB (bf16)
  run_layer(xbA, xbB, nullptr, basis0, comp0, q0, k0, xwb, wTb, ai, aj, coef,
            rstart, recs, stream);
  // ---- layer 1: xbB -> Cacc (f32 only)
  run_layer(xbB, nullptr, Cacc, basis1, comp1, q1, k1, xwb, wTb, ai, aj, coef,
            rstart, recs, stream);

  final_linear<<<(NPV + 255) / 256, 256, 0, stream>>>(Cacc, Wc, bc, (float*)d_out);
}

// Round 12
// 280.159 us; speedup vs baseline: 1.0090x; 1.0090x over previous
//
#include <hip/hip_runtime.h>
#include <hip/hip_bf16.h>
#include <math.h>

#define N_NODES 24576
#define NPV 8192
#define E_EDGES 393216
#define R_REL 6
#define B_BASES 8
#define HEADS 4
#define NEG_SLOPE 0.2f
#define NX (N_NODES * 128)
#define NK (N_NODES * R_REL)
#define SCAN_BLOCKS (NK / 256)  // 576

typedef unsigned short ushort_t;
using short8 = __attribute__((ext_vector_type(8))) short;
using f32x4 = __attribute__((ext_vector_type(4))) float;

__device__ __forceinline__ float lrelu(float x) { return x >= 0.f ? x : NEG_SLOPE * x; }
__device__ __forceinline__ float b2f(ushort_t u) {
  unsigned int v = ((unsigned int)u) << 16;
  float f;
  __builtin_memcpy(&f, &v, 4);
  return f;
}
__device__ __forceinline__ ushort_t f2b(float f) {
  __hip_bfloat16 h = __float2bfloat16(f);
  ushort_t u;
  __builtin_memcpy(&u, &h, 2);
  return u;
}

// ---------------------------------------------------------------------------
// gemm_proj_split: split-K projection, NO atomics, BM=128 W-traffic-minimal.
// grid (NPV/128, 9): z -> (view, K-chunk). r8/r9/r11 evidence: time tracks
// W re-staging traffic (each block converts its W panel every step), not
// occupancy. BM=128 halves W traffic vs BM=64 and doubles MFMA per staged
// byte. Synchronous single-buffer staging (r10: ILP pipeline netted zero).
// ---------------------------------------------------------------------------
__global__ __launch_bounds__(256) void gemm_proj_split(
    const float* __restrict__ x0, const float* __restrict__ x1,
    const float* __restrict__ x2, const float* __restrict__ w0,
    const float* __restrict__ w1, const float* __restrict__ w2,
    float* __restrict__ Ppart) {
  __shared__ __align__(16) ushort_t As[128 * 64];
  __shared__ __align__(16) ushort_t Ws[128 * 64];
  const int z = blockIdx.y;
  const float* A;
  const float* W;
  int K, kstart, ksteps;
  if (z < 4)      { A = x0; W = w0; K = 2000; kstart = z * 512;       ksteps = 8; }
  else if (z < 7) { A = x1; W = w1; K = 1500; kstart = (z - 4) * 512; ksteps = 8; }
  else            { A = x2; W = w2; K = 500;  kstart = (z - 7) * 256; ksteps = 4; }
  const int tid = threadIdx.x;
  const int wave = tid >> 6, lane = tid & 63;
  const int m0 = blockIdx.x * 128;
  const int wrow = wave * 32;  // each wave: 32 rows (2 strips of 16)

  f32x4 acc[2][8];
#pragma unroll
  for (int st = 0; st < 2; ++st)
#pragma unroll
    for (int n = 0; n < 8; ++n) acc[st][n] = (f32x4){0.f, 0.f, 0.f, 0.f};

  for (int step = 0; step < ksteps; ++step) {
    const int k0 = kstart + (step << 6);
    __syncthreads();
    // stage A tile (128 rows x 64 k): 4 chunks/thread, XOR-swizzled source
#pragma unroll
    for (int q = 0; q < 4; ++q) {
      int s = q * 256 + tid;
      int row = s >> 3, ch = s & 7;
      int gk = k0 + ((ch ^ (row & 7)) << 3);
      const float* gp = A + (long)(m0 + row) * K + gk;
      short8 o;
      if (gk + 8 <= K) {
        float4 a = *reinterpret_cast<const float4*>(gp);
        float4 b = *reinterpret_cast<const float4*>(gp + 4);
        o[0] = (short)f2b(a.x); o[1] = (short)f2b(a.y);
        o[2] = (short)f2b(a.z); o[3] = (short)f2b(a.w);
        o[4] = (short)f2b(b.x); o[5] = (short)f2b(b.y);
        o[6] = (short)f2b(b.z); o[7] = (short)f2b(b.w);
      } else {
#pragma unroll
        for (int j = 0; j < 8; ++j)
          o[j] = (gk + j < K) ? (short)f2b(gp[j]) : (short)0;
      }
      *reinterpret_cast<short8*>(As + s * 8) = o;
    }
    // stage W tile (128 rows x 64 k): 4 chunks/thread
#pragma unroll
    for (int q = 0; q < 4; ++q) {
      int s = q * 256 + tid;
      int row = s >> 3, ch = s & 7;
      int gk = k0 + ((ch ^ (row & 7)) << 3);
      const float* gp = W + (long)row * K + gk;
      short8 o;
      if (gk + 8 <= K) {
        float4 a = *reinterpret_cast<const float4*>(gp);
        float4 b = *reinterpret_cast<const float4*>(gp + 4);
        o[0] = (short)f2b(a.x); o[1] = (short)f2b(a.y);
        o[2] = (short)f2b(a.z); o[3] = (short)f2b(a.w);
        o[4] = (short)f2b(b.x); o[5] = (short)f2b(b.y);
        o[6] = (short)f2b(b.z); o[7] = (short)f2b(b.w);
      } else {
#pragma unroll
        for (int j = 0; j < 8; ++j)
          o[j] = (gk + j < K) ? (short)f2b(gp[j]) : (short)0;
      }
      *reinterpret_cast<short8*>(Ws + s * 8) = o;
    }
    __syncthreads();
#pragma unroll
    for (int kk = 0; kk < 2; ++kk) {
      short8 afrag[2];
#pragma unroll
      for (int st = 0; st < 2; ++st) {
        const int arow = wrow + st * 16 + (lane & 15);
        const int ach = (kk * 4 + (lane >> 4)) ^ (arow & 7);
        afrag[st] = *reinterpret_cast<const short8*>(As + arow * 64 + ach * 8);
      }
#pragma unroll
      for (int n = 0; n < 8; ++n) {
        const int brow = n * 16 + (lane & 15);
        const int bch = (kk * 4 + (lane >> 4)) ^ (brow & 7);
        short8 bfrag = *reinterpret_cast<const short8*>(Ws + brow * 64 + bch * 8);
        acc[0][n] = __builtin_amdgcn_mfma_f32_16x16x32_bf16(afrag[0], bfrag, acc[0][n], 0, 0, 0);
        acc[1][n] = __builtin_amdgcn_mfma_f32_16x16x32_bf16(afrag[1], bfrag, acc[1][n], 0, 0, 0);
      }
    }
  }
  const int cb = lane & 15;
  float* out = Ppart + (long)z * NPV * 128;
#pragma unroll
  for (int st = 0; st < 2; ++st) {
    const int rbase = m0 + wrow + st * 16 + (lane >> 4) * 4;
#pragma unroll
    for (int n = 0; n < 8; ++n) {
      int col = n * 16 + cb;
#pragma unroll
      for (int r = 0; r < 4; ++r)
        out[(long)(rbase + r) * 128 + col] = acc[st][n][r];
    }
  }
}

// proj_reduce: xb[n, c] = bf16(relu(sum_z Ppart[z][m, c] + bias_v[c]))
__global__ __launch_bounds__(256) void proj_reduce(
    const float* __restrict__ Ppart, const float* __restrict__ b0,
    const float* __restrict__ b1, const float* __restrict__ b2,
    ushort_t* __restrict__ xb) {
  int t = blockIdx.x * blockDim.x + threadIdx.x;
  if (t >= N_NODES * 16) return;
  int n = t >> 4, c0 = (t & 15) * 8;
  int v = n >> 13, m = n & (NPV - 1);
  int zb, zc;
  const float* bias;
  if (v == 0) { zb = 0; zc = 4; bias = b0; }
  else if (v == 1) { zb = 4; zc = 3; bias = b1; }
  else { zb = 7; zc = 2; bias = b2; }
  float s[8];
#pragma unroll
  for (int j = 0; j < 8; ++j) s[j] = bias[c0 + j];
  for (int zz = 0; zz < zc; ++zz) {
    const float* p = Ppart + ((long)(zb + zz) * NPV + m) * 128 + c0;
    float4 a = *reinterpret_cast<const float4*>(p);
    float4 b = *reinterpret_cast<const float4*>(p + 4);
    s[0] += a.x; s[1] += a.y; s[2] += a.z; s[3] += a.w;
    s[4] += b.x; s[5] += b.y; s[6] += b.z; s[7] += b.w;
  }
  short8 o;
#pragma unroll
  for (int j = 0; j < 8; ++j) {
    float vv = s[j] > 0.f ? s[j] : 0.f;
    o[j] = (short)f2b(vv);
  }
  *reinterpret_cast<short8*>(xb + (long)n * 128 + c0) = o;
}

// ---------------------------------------------------------------------------
// xw GEMM: xwb[r][M,128] = bf16(xb[M,128] @ w_r[128,128]^T), plus fused
// attention tables ai/aj = (xb@w_r) @ q / @ k from the f32 accumulators.
// ---------------------------------------------------------------------------
template <bool SPLIT, bool TABLES>
__global__ __launch_bounds__(256) void mfma_gemm_nt(
    const ushort_t* __restrict__ A, const ushort_t* __restrict__ W,
    float* __restrict__ Cacc, ushort_t* __restrict__ Cb,
    int Kp, int kChunk, long strideW, long strideCz,
    const float* __restrict__ qt, const float* __restrict__ kt,
    float* __restrict__ ai, float* __restrict__ aj) {
  __shared__ __align__(16) ushort_t As[64 * 64];
  __shared__ __align__(16) ushort_t Ws[128 * 64];
  const int tid = threadIdx.x;
  const int wave = tid >> 6, lane = tid & 63;
  const int m0 = blockIdx.x * 64;
  const int kbase = blockIdx.y * kChunk;
  const ushort_t* Wz = W + (long)blockIdx.z * strideW;

  f32x4 acc[8];
#pragma unroll
  for (int n = 0; n < 8; ++n) acc[n] = (f32x4){0.f, 0.f, 0.f, 0.f};

  for (int k0 = kbase; k0 < kbase + kChunk; k0 += 64) {
    __syncthreads();
#pragma unroll
    for (int q = 0; q < 2; ++q) {
      int s = q * 256 + tid;
      int row = s >> 3, ch = s & 7;
      int sch = ch ^ (row & 7);
      const ushort_t* g = A + (long)(m0 + row) * Kp + k0 + sch * 8;
      __builtin_amdgcn_global_load_lds(
          (const __attribute__((address_space(1))) unsigned int*)g,
          (__attribute__((address_space(3))) unsigned int*)(As + s * 8), 16, 0, 0);
    }
#pragma unroll
    for (int q = 0; q < 4; ++q) {
      int s = q * 256 + tid;
      int row = s >> 3, ch = s & 7;
      int sch = ch ^ (row & 7);
      const ushort_t* g = Wz + (long)row * Kp + k0 + sch * 8;
      __builtin_amdgcn_global_load_lds(
          (const __attribute__((address_space(1))) unsigned int*)g,
          (__attribute__((address_space(3))) unsigned int*)(Ws + s * 8), 16, 0, 0);
    }
    __syncthreads();
#pragma unroll
    for (int kk = 0; kk < 2; ++kk) {
      const int arow = wave * 16 + (lane & 15);
      const int ach = (kk * 4 + (lane >> 4)) ^ (arow & 7);
      short8 afrag = *reinterpret_cast<const short8*>(As + arow * 64 + ach * 8);
#pragma unroll
      for (int n = 0; n < 8; ++n) {
        const int brow = n * 16 + (lane & 15);
        const int bch = (kk * 4 + (lane >> 4)) ^ (brow & 7);
        short8 bfrag = *reinterpret_cast<const short8*>(Ws + brow * 64 + bch * 8);
        acc[n] = __builtin_amdgcn_mfma_f32_16x16x32_bf16(afrag, bfrag, acc[n], 0, 0, 0);
      }
    }
  }
  const int rbase = m0 + wave * 16 + (lane >> 4) * 4;
  const int cb = lane & 15;
  if (SPLIT) {
#pragma unroll
    for (int n = 0; n < 8; ++n) {
      int col = n * 16 + cb;
#pragma unroll
      for (int r = 0; r < 4; ++r)
        atomicAdd(&Cacc[(long)(rbase + r) * 128 + col], acc[n][r]);
    }
  } else {
    ushort_t* Cz = Cb + (long)blockIdx.z * strideCz;
#pragma unroll
    for (int n = 0; n < 8; ++n) {
      int col = n * 16 + cb;
#pragma unroll
      for (int r = 0; r < 4; ++r)
        Cz[(long)(rbase + r) * 128 + col] = f2b(acc[n][r]);
    }
  }
  if (TABLES) {
    float aq[4][4], ak[4][4];
#pragma unroll
    for (int r = 0; r < 4; ++r)
#pragma unroll
      for (int h = 0; h < 4; ++h) { aq[r][h] = 0.f; ak[r][h] = 0.f; }
#pragma unroll
    for (int n = 0; n < 8; ++n) {
      int col = n * 16 + cb;
      float4 qv = *reinterpret_cast<const float4*>(qt + (long)col * 4);
      float4 kv = *reinterpret_cast<const float4*>(kt + (long)col * 4);
#pragma unroll
      for (int r = 0; r < 4; ++r) {
        float x = acc[n][r];
        aq[r][0] += x * qv.x; aq[r][1] += x * qv.y;
        aq[r][2] += x * qv.z; aq[r][3] += x * qv.w;
        ak[r][0] += x * kv.x; ak[r][1] += x * kv.y;
        ak[r][2] += x * kv.z; ak[r][3] += x * kv.w;
      }
    }
#pragma unroll
    for (int mk = 1; mk < 16; mk <<= 1) {
#pragma unroll
      for (int r = 0; r < 4; ++r)
#pragma unroll
        for (int h = 0; h < 4; ++h) {
          aq[r][h] += __shfl_xor(aq[r][h], mk);
          ak[r][h] += __shfl_xor(ak[r][h], mk);
        }
    }
    int rr = cb >> 2, hh = cb & 3;
    long row = (long)blockIdx.z * N_NODES + rbase + rr;
    ai[row * 4 + hh] = aq[rr][hh];
    aj[row * 4 + hh] = ak[rr][hh];
  }
}

// ---------------------------------------------------------------------------
__global__ void fill_f32(float* __restrict__ p, long n, float v) {
  long i = blockIdx.x * (long)blockDim.x + threadIdx.x;
  long stride = (long)gridDim.x * blockDim.x;
  for (; i < n; i += stride) p[i] = v;
}

// wTb[r,o,i] = bf16( sum_b comp[r,b] * basis[b,i,o] )
__global__ void compute_wT_b(const float* __restrict__ comp,
                             const float* __restrict__ basis,
                             ushort_t* __restrict__ wTb) {
  int idx = blockIdx.x * blockDim.x + threadIdx.x;
  if (idx >= R_REL * 128 * 128) return;
  int r = idx >> 14;
  int rem = idx & 16383;
  int o = rem >> 7;
  int i = rem & 127;
  float s = 0.f;
#pragma unroll
  for (int b = 0; b < B_BASES; ++b)
    s += comp[r * B_BASES + b] * basis[((b << 7) + i) * 128 + o];
  wTb[((long)(r << 7) + o) * 128 + i] = f2b(s);
}

// ---------------------------------------------------------------------------
// CSR build keyed by (dst*6 + rel): count -> hierarchical scan -> scatter.
// ---------------------------------------------------------------------------
__global__ void count_key(const int* __restrict__ dst, const int* __restrict__ et,
                          int* __restrict__ cnt, int E) {
  int e = blockIdx.x * blockDim.x + threadIdx.x;
  if (e < E) atomicAdd(&cnt[dst[e] * R_REL + et[e]], 1);
}

__global__ __launch_bounds__(256) void scan_block(const int* __restrict__ cnt,
                                                  int* __restrict__ start,
                                                  int* __restrict__ blockSums) {
  __shared__ int sm[256];
  const int t = threadIdx.x;
  const int i = blockIdx.x * 256 + t;
  int v = cnt[i];
  sm[t] = v;
  __syncthreads();
  for (int off = 1; off < 256; off <<= 1) {
    int u = (t >= off) ? sm[t - off] : 0;
    __syncthreads();
    sm[t] += u;
    __syncthreads();
  }
  start[i] = sm[t] - v;  // exclusive
  if (t == 255) blockSums[blockIdx.x] = sm[255];
}

__global__ __launch_bounds__(SCAN_BLOCKS) void scan_sums(int* __restrict__ blockSums) {
  __shared__ int sm[SCAN_BLOCKS];
  const int t = threadIdx.x;
  int v = blockSums[t];
  sm[t] = v;
  __syncthreads();
  for (int off = 1; off < SCAN_BLOCKS; off <<= 1) {
    int u = (t >= off) ? sm[t - off] : 0;
    __syncthreads();
    sm[t] += u;
    __syncthreads();
  }
  blockSums[t] = sm[t] - v;  // exclusive
}

__global__ __launch_bounds__(256) void add_offsets(int* __restrict__ start,
                                                   const int* __restrict__ blockSums) {
  int i = blockIdx.x * 256 + threadIdx.x;
  start[i] += blockSums[blockIdx.x];
  if (i == 0) start[NK] = E_EDGES;
}

__global__ void scatter_edges(const int* __restrict__ src, const int* __restrict__ dst,
                              const int* __restrict__ et, const int* __restrict__ start,
                              int* __restrict__ cursor, int* __restrict__ recs, int E) {
  int e = blockIdx.x * blockDim.x + threadIdx.x;
  if (e >= E) return;
  int key = dst[e] * R_REL + et[e];
  int pos = start[key] + atomicAdd(&cursor[key], 1);
  recs[pos] = src[e] | (et[e] << 16);
}

// ---------------------------------------------------------------------------
// seg_softmax: one thread per (dst,rel) segment -> per-edge coef[h*E + pos].
// ---------------------------------------------------------------------------
__global__ __launch_bounds__(256) void seg_softmax(
    const int* __restrict__ rstart, const int* __restrict__ recs,
    const float* __restrict__ ai, const float* __restrict__ aj,
    float* __restrict__ coef) {
  int seg = blockIdx.x * blockDim.x + threadIdx.x;
  if (seg >= NK) return;
  int p0 = rstart[seg], p1 = rstart[seg + 1];
  if (p0 == p1) return;
  int d = seg / R_REL, r = seg - d * R_REL;
  float4 av = *reinterpret_cast<const float4*>(ai + ((long)r * N_NODES + d) * 4);
  float degf = (float)(rstart[(d + 1) * R_REL] - rstart[d * R_REL]);
  float m[4] = {-INFINITY, -INFINITY, -INFINITY, -INFINITY};
  float sum[4] = {0.f, 0.f, 0.f, 0.f};
  for (int p = p0; p < p1; ++p) {
    int s = recs[p] & 0xFFFF;
    float4 bv = *reinterpret_cast<const float4*>(aj + ((long)r * N_NODES + s) * 4);
    float al[4] = {lrelu(av.x + bv.x), lrelu(av.y + bv.y),
                   lrelu(av.z + bv.z), lrelu(av.w + bv.w)};
#pragma unroll
    for (int h = 0; h < 4; ++h) {
      float nm = fmaxf(m[h], al[h]);
      sum[h] = sum[h] * __expf(m[h] - nm) + __expf(al[h] - nm);
      m[h] = nm;
    }
  }
  float rs[4];
#pragma unroll
  for (int h = 0; h < 4; ++h) rs[h] = degf / (sum[h] + 1e-16f);
  for (int p = p0; p < p1; ++p) {
    int s = recs[p] & 0xFFFF;
    float4 bv = *reinterpret_cast<const float4*>(aj + ((long)r * N_NODES + s) * 4);
    float al[4] = {lrelu(av.x + bv.x), lrelu(av.y + bv.y),
                   lrelu(av.z + bv.z), lrelu(av.w + bv.w)};
#pragma unroll
    for (int h = 0; h < 4; ++h)
      coef[(long)h * E_EDGES + p] = __expf(al[h] - m[h]) * rs[h];
  }
}

// ---------------------------------------------------------------------------
// fused_agg: one wave per dst node; pure gather-accumulate over xwb.
// ---------------------------------------------------------------------------
__global__ __launch_bounds__(256) void fused_agg(
    const int* __restrict__ rstart, const int* __restrict__ recs,
    const float* __restrict__ coef, const ushort_t* __restrict__ xwb,
    ushort_t* __restrict__ xb_out, float* __restrict__ fout) {
  const int wave = threadIdx.x >> 6, lane = threadIdx.x & 63;
  const int d = blockIdx.x * 4 + wave;
  const int s0 = rstart[d * R_REL], s1 = rstart[(d + 1) * R_REL];
  const float* cfp = coef + (long)(lane >> 4) * E_EDGES;
  float acc0 = 0.f, acc1 = 0.f;
#pragma unroll 4
  for (int pos = s0; pos < s1; ++pos) {
    int rec = recs[pos];
    float cf = cfp[pos];
    int s = rec & 0xFFFF, r = rec >> 16;
    unsigned int pk = *reinterpret_cast<const unsigned int*>(
        xwb + (((long)r * N_NODES + s) << 7) + 2 * lane);
    acc0 += cf * b2f((ushort_t)(pk & 0xFFFF));
    acc1 += cf * b2f((ushort_t)(pk >> 16));
  }
  if (xb_out) {
    unsigned int po = ((unsigned int)f2b(acc1) << 16) | (unsigned int)f2b(acc0);
    *reinterpret_cast<unsigned int*>(xb_out + ((long)d << 7) + 2 * lane) = po;
  }
  if (fout) {
    *reinterpret_cast<float2*>(fout + ((long)d << 7) + 2 * lane) =
        make_float2(acc0, acc1);
  }
}

__global__ void final_linear(const float* __restrict__ x, const float* __restrict__ Wc,
                             const float* __restrict__ bc, float* __restrict__ out) {
  __shared__ float wcs[4 * 384];
  for (int t = threadIdx.x; t < 4 * 384; t += blockDim.x) wcs[t] = Wc[t];
  __syncthreads();
  int i = blockIdx.x * blockDim.x + threadIdx.x;
  if (i >= NPV) return;
  float acc[4] = {0.f, 0.f, 0.f, 0.f};
  for (int v = 0; v < 3; ++v) {
    const float* xr = x + ((long)v * NPV + i) * 128;
    for (int c = 0; c < 128; c += 4) {
      float4 xv = *reinterpret_cast<const float4*>(xr + c);
#pragma unroll
      for (int l = 0; l < 4; ++l) {
        const float* w = wcs + l * 384 + v * 128 + c;
        acc[l] += xv.x * w[0] + xv.y * w[1] + xv.z * w[2] + xv.w * w[3];
      }
    }
  }
#pragma unroll
  for (int l = 0; l < 4; ++l) out[(long)i * 4 + l] = acc[l] + bc[l];
}

// ---------------------------------------------------------------------------
static void run_layer(const ushort_t* xb_in, ushort_t* xb_out, float* fout,
                      const float* basis, const float* comp, const float* q,
                      const float* k, ushort_t* xwb, ushort_t* wTb, float* ai,
                      float* aj, float* coef, const int* rstart, const int* recs,
                      hipStream_t stream) {
  compute_wT_b<<<(R_REL * 128 * 128 + 255) / 256, 256, 0, stream>>>(comp, basis, wTb);
  mfma_gemm_nt<false, true><<<dim3(N_NODES / 64, 1, R_REL), 256, 0, stream>>>(
      xb_in, wTb, nullptr, xwb, 128, 128, 128 * 128, (long)N_NODES * 128,
      q, k, ai, aj);
  seg_softmax<<<(NK + 255) / 256, 256, 0, stream>>>(rstart, recs, ai, aj, coef);
  fused_agg<<<N_NODES / 4, 256, 0, stream>>>(rstart, recs, coef, xwb, xb_out, fout);
}

extern "C" void kernel_launch(void* const* d_in, const int* in_sizes, int n_in,
                              void* d_out, int out_size, void* d_ws, size_t ws_size,
                              hipStream_t stream) {
  const float* x0 = (const float*)d_in[0];
  const float* x1 = (const float*)d_in[1];
  const float* x2 = (const float*)d_in[2];
  const int* edge_index = (const int*)d_in[3];
  const int* edge_type = (const int*)d_in[4];
  const float* Wp0 = (const float*)d_in[5];
  const float* bp0 = (const float*)d_in[6];
  const float* Wp1 = (const float*)d_in[7];
  const float* bp1 = (const float*)d_in[8];
  const float* Wp2 = (const float*)d_in[9];
  const float* bp2 = (const float*)d_in[10];
  const float* basis0 = (const float*)d_in[11];
  const float* comp0 = (const float*)d_in[12];
  const float* q0 = (const float*)d_in[13];
  const float* k0 = (const float*)d_in[14];
  const float* basis1 = (const float*)d_in[15];
  const float* comp1 = (const float*)d_in[16];
  const float* q1 = (const float*)d_in[17];
  const float* k1 = (const float*)d_in[18];
  const float* Wc = (const float*)d_in[19];
  const float* bc = (const float*)d_in[20];

  const int* src = edge_index;
  const int* dst = edge_index + E_EDGES;

  // ---- workspace layout ----
  char* w = (char*)d_ws;
  auto alloc = [&](long bytes) {
    char* p = w;
    w += (bytes + 255) & ~255L;
    return p;
  };
  ushort_t* xbA  = (ushort_t*)alloc((long)NX * 2);
  ushort_t* xbB  = (ushort_t*)alloc((long)NX * 2);
  ushort_t* xwb  = (ushort_t*)alloc(9L * NPV * 128 * 4);  // aliased: Ppart (f32) then xwb (bf16)
  ushort_t* wTb  = (ushort_t*)alloc((long)R_REL * 128 * 128 * 2);
  float* Cacc    = (float*)alloc((long)NX * 4);
  float* ai      = (float*)alloc((long)R_REL * N_NODES * 4 * 4);
  float* aj      = (float*)alloc((long)R_REL * N_NODES * 4 * 4);
  float* coef    = (float*)alloc((long)HEADS * E_EDGES * 4);
  int* cnt       = (int*)alloc((long)NK * 4);
  int* cursor    = (int*)alloc((long)NK * 4);
  int* rstart    = (int*)alloc((long)(NK + 1) * 4);
  int* recs      = (int*)alloc((long)E_EDGES * 4);
  int* blockSums = (int*)alloc((long)SCAN_BLOCKS * 4);
  float* Ppart   = (float*)xwb;  // alias: projection partials die before xwb is written

  // ---- projections: BM=128 split-K (no atomics) -> partials -> reduce
  gemm_proj_split<<<dim3(NPV / 128, 9), 256, 0, stream>>>(
      x0, x1, x2, Wp0, Wp1, Wp2, Ppart);
  proj_reduce<<<(N_NODES * 16 + 255) / 256, 256, 0, stream>>>(
      Ppart, bp0, bp1, bp2, xbA);

  // ---- CSR build keyed by (dst,rel) (once; shared by both layers)
  fill_f32<<<96, 256, 0, stream>>>((float*)cnt, 2L * NK, 0.f);  // cnt+cursor adjacent
  count_key<<<E_EDGES / 256, 256, 0, stream>>>(dst, edge_type, cnt, E_EDGES);
  scan_block<<<SCAN_BLOCKS, 256, 0, stream>>>(cnt, rstart, blockSums);
  scan_sums<<<1, SCAN_BLOCKS, 0, stream>>>(blockSums);
  add_offsets<<<SCAN_BLOCKS, 256, 0, stream>>>(rstart, blockSums);
  scatter_edges<<<E_EDGES / 256, 256, 0, stream>>>(src, dst, edge_type, rstart,
                                                   cursor, recs, E_EDGES);

  // ---- layer 0: xbA -> xbB (bf16)
  run_layer(xbA, xbB, nullptr, basis0, comp0, q0, k0, xwb, wTb, ai, aj, coef,
            rstart, recs, stream);
  // ---- layer 1: xbB -> Cacc (f32 only)
  run_layer(xbB, nullptr, Cacc, basis1, comp1, q1, k1, xwb, wTb, ai, aj, coef,
            rstart, recs, stream);

  final_linear<<<(NPV + 255) / 256, 256, 0, stream>>>(Cacc, Wc, bc, (float*)d_out);
}

// Round 13
// 278.754 us; speedup vs baseline: 1.0141x; 1.0050x over previous
//
#include <hip/hip_runtime.h>
#include <hip/hip_bf16.h>
#include <math.h>

#define N_NODES 24576
#define NPV 8192
#define E_EDGES 393216
#define R_REL 6
#define B_BASES 8
#define HEADS 4
#define NEG_SLOPE 0.2f
#define NX (N_NODES * 128)
#define NK (N_NODES * R_REL)
#define SCAN_BLOCKS (NK / 256)  // 576
#define WPAD 2048               // padded K stride for projection weights (bf16)

typedef unsigned short ushort_t;
using short8 = __attribute__((ext_vector_type(8))) short;
using f32x4 = __attribute__((ext_vector_type(4))) float;

__device__ __forceinline__ float lrelu(float x) { return x >= 0.f ? x : NEG_SLOPE * x; }
__device__ __forceinline__ float b2f(ushort_t u) {
  unsigned int v = ((unsigned int)u) << 16;
  float f;
  __builtin_memcpy(&f, &v, 4);
  return f;
}
__device__ __forceinline__ ushort_t f2b(float f) {
  __hip_bfloat16 h = __float2bfloat16(f);
  ushort_t u;
  __builtin_memcpy(&u, &h, 2);
  return u;
}

// ---------------------------------------------------------------------------
// cvt_pad: f32 [M,K] -> bf16 [M,Kp], zero-padded (used for proj weights).
// ---------------------------------------------------------------------------
__global__ void cvt_pad_bf16(const float* __restrict__ in, ushort_t* __restrict__ out,
                             int M, int K, int Kp) {
  int kp8 = Kp >> 3;
  int total = M * kp8;
  for (int t = blockIdx.x * blockDim.x + threadIdx.x; t < total;
       t += gridDim.x * blockDim.x) {
    int row = t / kp8;
    int c0 = (t - row * kp8) * 8;
    short8 o;
    if (c0 + 7 < K) {
      const float4 a = *reinterpret_cast<const float4*>(in + (long)row * K + c0);
      const float4 b = *reinterpret_cast<const float4*>(in + (long)row * K + c0 + 4);
      o[0] = (short)f2b(a.x); o[1] = (short)f2b(a.y);
      o[2] = (short)f2b(a.z); o[3] = (short)f2b(a.w);
      o[4] = (short)f2b(b.x); o[5] = (short)f2b(b.y);
      o[6] = (short)f2b(b.z); o[7] = (short)f2b(b.w);
    } else {
#pragma unroll
      for (int j = 0; j < 8; ++j) {
        int c = c0 + j;
        float v = (c < K) ? in[(long)row * K + c] : 0.f;
        o[j] = (short)f2b(v);
      }
    }
    *reinterpret_cast<short8*>(out + (long)row * Kp + c0) = o;
  }
}

// ---------------------------------------------------------------------------
// gemm_proj_split v2: split-K projection via global_load_lds (async DMA).
// A staged as raw f32 into LDS (no cvt in staging; fragment cvt after
// ds_read). W pre-converted to padded bf16 (zero-pad -> tail-safe).
// XOR-chunk swizzle on the GLOBAL source (LDS dest linear, rule #21).
// Tail steps (K not /64) reg-stage A with zero guards; garbage A cols
// beyond K hit zero W pad.  grid (NPV/64, 9).
// ---------------------------------------------------------------------------
__global__ __launch_bounds__(256) void gemm_proj_split(
    const float* __restrict__ x0, const float* __restrict__ x1,
    const float* __restrict__ x2, const ushort_t* __restrict__ wb,
    float* __restrict__ Ppart) {
  __shared__ __align__(16) float Af[64 * 64];      // 16KB f32 A tile
  __shared__ __align__(16) ushort_t Ws[128 * 64];  // 16KB bf16 W tile
  const int z = blockIdx.y;
  const float* A;
  const ushort_t* W;
  int K, kstart, kend;
  if (z < 4) {
    A = x0; W = wb; K = 2000; kstart = z * 512;
  } else if (z < 7) {
    A = x1; W = wb + 128L * WPAD; K = 1500; kstart = (z - 4) * 512;
  } else {
    A = x2; W = wb + 256L * WPAD; K = 500; kstart = (z - 7) * 256;
  }
  kend = kstart + ((z < 7) ? 512 : 256);
  if (kend > K) kend = K;
  const int nfull = (kend - kstart) >> 6;
  const int tail = (kend - kstart) & 63;
  const int nsteps = nfull + (tail ? 1 : 0);

  const int tid = threadIdx.x;
  const int wave = tid >> 6, lane = tid & 63;
  const int m0 = blockIdx.x * 64;

  f32x4 acc[8];
#pragma unroll
  for (int n = 0; n < 8; ++n) acc[n] = (f32x4){0.f, 0.f, 0.f, 0.f};

  for (int step = 0; step < nsteps; ++step) {
    const int k0 = kstart + (step << 6);
    __syncthreads();
    if (step < nfull) {
      // A: 4 f32 16B-chunks per thread, async DMA, source-swizzled
#pragma unroll
      for (int q = 0; q < 4; ++q) {
        int s = q * 256 + tid;
        int row = s >> 4, ch = s & 15;
        int sch = ch ^ (row & 15);
        const float* g = A + (long)(m0 + row) * K + k0 + sch * 4;
        __builtin_amdgcn_global_load_lds(
            (const __attribute__((address_space(1))) unsigned int*)g,
            (__attribute__((address_space(3))) unsigned int*)(Af + s * 4), 16, 0, 0);
      }
    } else {
      // tail: reg-stage A with zero guard (kend == K here by construction)
#pragma unroll
      for (int q = 0; q < 4; ++q) {
        int s = q * 256 + tid;
        int row = s >> 4, ch = s & 15;
        int sch = ch ^ (row & 15);
        int gk = k0 + sch * 4;
        const float* gp = A + (long)(m0 + row) * K + gk;
        float4 v = make_float4(0.f, 0.f, 0.f, 0.f);
#pragma unroll
        for (int j = 0; j < 4; ++j)
          if (gk + j < kend) (&v.x)[j] = gp[j];
        *reinterpret_cast<float4*>(Af + s * 4) = v;
      }
    }
    // W: 4 bf16 16B-chunks per thread, async DMA (padded -> always safe)
#pragma unroll
    for (int q = 0; q < 4; ++q) {
      int s = q * 256 + tid;
      int row = s >> 3, ch = s & 7;
      int sch = ch ^ (row & 7);
      const ushort_t* g = W + (long)row * WPAD + k0 + sch * 8;
      __builtin_amdgcn_global_load_lds(
          (const __attribute__((address_space(1))) unsigned int*)g,
          (__attribute__((address_space(3))) unsigned int*)(Ws + s * 8), 16, 0, 0);
    }
    __syncthreads();
#pragma unroll
    for (int kk = 0; kk < 2; ++kk) {
      const int arow = wave * 16 + (lane & 15);
      const int t = kk * 4 + (lane >> 4);
      const int sc0 = (2 * t) ^ (arow & 15);
      const int sc1 = (2 * t + 1) ^ (arow & 15);
      f32x4 a0 = *reinterpret_cast<const f32x4*>(Af + arow * 64 + sc0 * 4);
      f32x4 a1 = *reinterpret_cast<const f32x4*>(Af + arow * 64 + sc1 * 4);
      short8 afrag;
      afrag[0] = (short)f2b(a0[0]); afrag[1] = (short)f2b(a0[1]);
      afrag[2] = (short)f2b(a0[2]); afrag[3] = (short)f2b(a0[3]);
      afrag[4] = (short)f2b(a1[0]); afrag[5] = (short)f2b(a1[1]);
      afrag[6] = (short)f2b(a1[2]); afrag[7] = (short)f2b(a1[3]);
#pragma unroll
      for (int n = 0; n < 8; ++n) {
        const int brow = n * 16 + (lane & 15);
        const int bch = (kk * 4 + (lane >> 4)) ^ (brow & 7);
        short8 bfrag = *reinterpret_cast<const short8*>(Ws + brow * 64 + bch * 8);
        acc[n] = __builtin_amdgcn_mfma_f32_16x16x32_bf16(afrag, bfrag, acc[n], 0, 0, 0);
      }
    }
  }
  const int rbase = m0 + wave * 16 + (lane >> 4) * 4;
  const int cb = lane & 15;
  float* out = Ppart + (long)z * NPV * 128;
#pragma unroll
  for (int n = 0; n < 8; ++n) {
    int col = n * 16 + cb;
#pragma unroll
    for (int r = 0; r < 4; ++r)
      out[(long)(rbase + r) * 128 + col] = acc[n][r];
  }
}

// proj_reduce: xb[n, c] = bf16(relu(sum_z Ppart[z][m, c] + bias_v[c]))
__global__ __launch_bounds__(256) void proj_reduce(
    const float* __restrict__ Ppart, const float* __restrict__ b0,
    const float* __restrict__ b1, const float* __restrict__ b2,
    ushort_t* __restrict__ xb) {
  int t = blockIdx.x * blockDim.x + threadIdx.x;
  if (t >= N_NODES * 16) return;
  int n = t >> 4, c0 = (t & 15) * 8;
  int v = n >> 13, m = n & (NPV - 1);
  int zb, zc;
  const float* bias;
  if (v == 0) { zb = 0; zc = 4; bias = b0; }
  else if (v == 1) { zb = 4; zc = 3; bias = b1; }
  else { zb = 7; zc = 2; bias = b2; }
  float s[8];
#pragma unroll
  for (int j = 0; j < 8; ++j) s[j] = bias[c0 + j];
  for (int zz = 0; zz < zc; ++zz) {
    const float* p = Ppart + ((long)(zb + zz) * NPV + m) * 128 + c0;
    float4 a = *reinterpret_cast<const float4*>(p);
    float4 b = *reinterpret_cast<const float4*>(p + 4);
    s[0] += a.x; s[1] += a.y; s[2] += a.z; s[3] += a.w;
    s[4] += b.x; s[5] += b.y; s[6] += b.z; s[7] += b.w;
  }
  short8 o;
#pragma unroll
  for (int j = 0; j < 8; ++j) {
    float vv = s[j] > 0.f ? s[j] : 0.f;
    o[j] = (short)f2b(vv);
  }
  *reinterpret_cast<short8*>(xb + (long)n * 128 + c0) = o;
}

// ---------------------------------------------------------------------------
// xw GEMM: xwb[r][M,128] = bf16(xb[M,128] @ w_r[128,128]^T), plus fused
// attention tables ai/aj = (xb@w_r) @ q / @ k from the f32 accumulators.
// ---------------------------------------------------------------------------
template <bool SPLIT, bool TABLES>
__global__ __launch_bounds__(256) void mfma_gemm_nt(
    const ushort_t* __restrict__ A, const ushort_t* __restrict__ W,
    float* __restrict__ Cacc, ushort_t* __restrict__ Cb,
    int Kp, int kChunk, long strideW, long strideCz,
    const float* __restrict__ qt, const float* __restrict__ kt,
    float* __restrict__ ai, float* __restrict__ aj) {
  __shared__ __align__(16) ushort_t As[64 * 64];
  __shared__ __align__(16) ushort_t Ws[128 * 64];
  const int tid = threadIdx.x;
  const int wave = tid >> 6, lane = tid & 63;
  const int m0 = blockIdx.x * 64;
  const int kbase = blockIdx.y * kChunk;
  const ushort_t* Wz = W + (long)blockIdx.z * strideW;

  f32x4 acc[8];
#pragma unroll
  for (int n = 0; n < 8; ++n) acc[n] = (f32x4){0.f, 0.f, 0.f, 0.f};

  for (int k0 = kbase; k0 < kbase + kChunk; k0 += 64) {
    __syncthreads();
#pragma unroll
    for (int q = 0; q < 2; ++q) {
      int s = q * 256 + tid;
      int row = s >> 3, ch = s & 7;
      int sch = ch ^ (row & 7);
      const ushort_t* g = A + (long)(m0 + row) * Kp + k0 + sch * 8;
      __builtin_amdgcn_global_load_lds(
          (const __attribute__((address_space(1))) unsigned int*)g,
          (__attribute__((address_space(3))) unsigned int*)(As + s * 8), 16, 0, 0);
    }
#pragma unroll
    for (int q = 0; q < 4; ++q) {
      int s = q * 256 + tid;
      int row = s >> 3, ch = s & 7;
      int sch = ch ^ (row & 7);
      const ushort_t* g = Wz + (long)row * Kp + k0 + sch * 8;
      __builtin_amdgcn_global_load_lds(
          (const __attribute__((address_space(1))) unsigned int*)g,
          (__attribute__((address_space(3))) unsigned int*)(Ws + s * 8), 16, 0, 0);
    }
    __syncthreads();
#pragma unroll
    for (int kk = 0; kk < 2; ++kk) {
      const int arow = wave * 16 + (lane & 15);
      const int ach = (kk * 4 + (lane >> 4)) ^ (arow & 7);
      short8 afrag = *reinterpret_cast<const short8*>(As + arow * 64 + ach * 8);
#pragma unroll
      for (int n = 0; n < 8; ++n) {
        const int brow = n * 16 + (lane & 15);
        const int bch = (kk * 4 + (lane >> 4)) ^ (brow & 7);
        short8 bfrag = *reinterpret_cast<const short8*>(Ws + brow * 64 + bch * 8);
        acc[n] = __builtin_amdgcn_mfma_f32_16x16x32_bf16(afrag, bfrag, acc[n], 0, 0, 0);
      }
    }
  }
  const int rbase = m0 + wave * 16 + (lane >> 4) * 4;
  const int cb = lane & 15;
  if (SPLIT) {
#pragma unroll
    for (int n = 0; n < 8; ++n) {
      int col = n * 16 + cb;
#pragma unroll
      for (int r = 0; r < 4; ++r)
        atomicAdd(&Cacc[(long)(rbase + r) * 128 + col], acc[n][r]);
    }
  } else {
    ushort_t* Cz = Cb + (long)blockIdx.z * strideCz;
#pragma unroll
    for (int n = 0; n < 8; ++n) {
      int col = n * 16 + cb;
#pragma unroll
      for (int r = 0; r < 4; ++r)
        Cz[(long)(rbase + r) * 128 + col] = f2b(acc[n][r]);
    }
  }
  if (TABLES) {
    float aq[4][4], ak[4][4];
#pragma unroll
    for (int r = 0; r < 4; ++r)
#pragma unroll
      for (int h = 0; h < 4; ++h) { aq[r][h] = 0.f; ak[r][h] = 0.f; }
#pragma unroll
    for (int n = 0; n < 8; ++n) {
      int col = n * 16 + cb;
      float4 qv = *reinterpret_cast<const float4*>(qt + (long)col * 4);
      float4 kv = *reinterpret_cast<const float4*>(kt + (long)col * 4);
#pragma unroll
      for (int r = 0; r < 4; ++r) {
        float x = acc[n][r];
        aq[r][0] += x * qv.x; aq[r][1] += x * qv.y;
        aq[r][2] += x * qv.z; aq[r][3] += x * qv.w;
        ak[r][0] += x * kv.x; ak[r][1] += x * kv.y;
        ak[r][2] += x * kv.z; ak[r][3] += x * kv.w;
      }
    }
#pragma unroll
    for (int mk = 1; mk < 16; mk <<= 1) {
#pragma unroll
      for (int r = 0; r < 4; ++r)
#pragma unroll
        for (int h = 0; h < 4; ++h) {
          aq[r][h] += __shfl_xor(aq[r][h], mk);
          ak[r][h] += __shfl_xor(ak[r][h], mk);
        }
    }
    int rr = cb >> 2, hh = cb & 3;
    long row = (long)blockIdx.z * N_NODES + rbase + rr;
    ai[row * 4 + hh] = aq[rr][hh];
    aj[row * 4 + hh] = ak[rr][hh];
  }
}

// ---------------------------------------------------------------------------
__global__ void fill_f32(float* __restrict__ p, long n, float v) {
  long i = blockIdx.x * (long)blockDim.x + threadIdx.x;
  long stride = (long)gridDim.x * blockDim.x;
  for (; i < n; i += stride) p[i] = v;
}

// wTb[r,o,i] = bf16( sum_b comp[r,b] * basis[b,i,o] )
__global__ void compute_wT_b(const float* __restrict__ comp,
                             const float* __restrict__ basis,
                             ushort_t* __restrict__ wTb) {
  int idx = blockIdx.x * blockDim.x + threadIdx.x;
  if (idx >= R_REL * 128 * 128) return;
  int r = idx >> 14;
  int rem = idx & 16383;
  int o = rem >> 7;
  int i = rem & 127;
  float s = 0.f;
#pragma unroll
  for (int b = 0; b < B_BASES; ++b)
    s += comp[r * B_BASES + b] * basis[((b << 7) + i) * 128 + o];
  wTb[((long)(r << 7) + o) * 128 + i] = f2b(s);
}

// ---------------------------------------------------------------------------
// CSR build keyed by (dst*6 + rel): count -> hierarchical scan -> scatter.
// ---------------------------------------------------------------------------
__global__ void count_key(const int* __restrict__ dst, const int* __restrict__ et,
                          int* __restrict__ cnt, int E) {
  int e = blockIdx.x * blockDim.x + threadIdx.x;
  if (e < E) atomicAdd(&cnt[dst[e] * R_REL + et[e]], 1);
}

__global__ __launch_bounds__(256) void scan_block(const int* __restrict__ cnt,
                                                  int* __restrict__ start,
                                                  int* __restrict__ blockSums) {
  __shared__ int sm[256];
  const int t = threadIdx.x;
  const int i = blockIdx.x * 256 + t;
  int v = cnt[i];
  sm[t] = v;
  __syncthreads();
  for (int off = 1; off < 256; off <<= 1) {
    int u = (t >= off) ? sm[t - off] : 0;
    __syncthreads();
    sm[t] += u;
    __syncthreads();
  }
  start[i] = sm[t] - v;  // exclusive
  if (t == 255) blockSums[blockIdx.x] = sm[255];
}

__global__ __launch_bounds__(SCAN_BLOCKS) void scan_sums(int* __restrict__ blockSums) {
  __shared__ int sm[SCAN_BLOCKS];
  const int t = threadIdx.x;
  int v = blockSums[t];
  sm[t] = v;
  __syncthreads();
  for (int off = 1; off < SCAN_BLOCKS; off <<= 1) {
    int u = (t >= off) ? sm[t - off] : 0;
    __syncthreads();
    sm[t] += u;
    __syncthreads();
  }
  blockSums[t] = sm[t] - v;  // exclusive
}

__global__ __launch_bounds__(256) void add_offsets(int* __restrict__ start,
                                                   const int* __restrict__ blockSums) {
  int i = blockIdx.x * 256 + threadIdx.x;
  start[i] += blockSums[blockIdx.x];
  if (i == 0) start[NK] = E_EDGES;
}

__global__ void scatter_edges(const int* __restrict__ src, const int* __restrict__ dst,
                              const int* __restrict__ et, const int* __restrict__ start,
                              int* __restrict__ cursor, int* __restrict__ recs, int E) {
  int e = blockIdx.x * blockDim.x + threadIdx.x;
  if (e >= E) return;
  int key = dst[e] * R_REL + et[e];
  int pos = start[key] + atomicAdd(&cursor[key], 1);
  recs[pos] = src[e] | (et[e] << 16);
}

// ---------------------------------------------------------------------------
// seg_softmax: one thread per (dst,rel) segment -> per-edge coef[h*E + pos].
// ---------------------------------------------------------------------------
__global__ __launch_bounds__(256) void seg_softmax(
    const int* __restrict__ rstart, const int* __restrict__ recs,
    const float* __restrict__ ai, const float* __restrict__ aj,
    float* __restrict__ coef) {
  int seg = blockIdx.x * blockDim.x + threadIdx.x;
  if (seg >= NK) return;
  int p0 = rstart[seg], p1 = rstart[seg + 1];
  if (p0 == p1) return;
  int d = seg / R_REL, r = seg - d * R_REL;
  float4 av = *reinterpret_cast<const float4*>(ai + ((long)r * N_NODES + d) * 4);
  float degf = (float)(rstart[(d + 1) * R_REL] - rstart[d * R_REL]);
  float m[4] = {-INFINITY, -INFINITY, -INFINITY, -INFINITY};
  float sum[4] = {0.f, 0.f, 0.f, 0.f};
  for (int p = p0; p < p1; ++p) {
    int s = recs[p] & 0xFFFF;
    float4 bv = *reinterpret_cast<const float4*>(aj + ((long)r * N_NODES + s) * 4);
    float al[4] = {lrelu(av.x + bv.x), lrelu(av.y + bv.y),
                   lrelu(av.z + bv.z), lrelu(av.w + bv.w)};
#pragma unroll
    for (int h = 0; h < 4; ++h) {
      float nm = fmaxf(m[h], al[h]);
      sum[h] = sum[h] * __expf(m[h] - nm) + __expf(al[h] - nm);
      m[h] = nm;
    }
  }
  float rs[4];
#pragma unroll
  for (int h = 0; h < 4; ++h) rs[h] = degf / (sum[h] + 1e-16f);
  for (int p = p0; p < p1; ++p) {
    int s = recs[p] & 0xFFFF;
    float4 bv = *reinterpret_cast<const float4*>(aj + ((long)r * N_NODES + s) * 4);
    float al[4] = {lrelu(av.x + bv.x), lrelu(av.y + bv.y),
                   lrelu(av.z + bv.z), lrelu(av.w + bv.w)};
#pragma unroll
    for (int h = 0; h < 4; ++h)
      coef[(long)h * E_EDGES + p] = __expf(al[h] - m[h]) * rs[h];
  }
}

// ---------------------------------------------------------------------------
// fused_agg: one wave per dst node; pure gather-accumulate over xwb.
// ---------------------------------------------------------------------------
__global__ __launch_bounds__(256) void fused_agg(
    const int* __restrict__ rstart, const int* __restrict__ recs,
    const float* __restrict__ coef, const ushort_t* __restrict__ xwb,
    ushort_t* __restrict__ xb_out, float* __restrict__ fout) {
  const int wave = threadIdx.x >> 6, lane = threadIdx.x & 63;
  const int d = blockIdx.x * 4 + wave;
  const int s0 = rstart[d * R_REL], s1 = rstart[(d + 1) * R_REL];
  const float* cfp = coef + (long)(lane >> 4) * E_EDGES;
  float acc0 = 0.f, acc1 = 0.f;
#pragma unroll 4
  for (int pos = s0; pos < s1; ++pos) {
    int rec = recs[pos];
    float cf = cfp[pos];
    int s = rec & 0xFFFF, r = rec >> 16;
    unsigned int pk = *reinterpret_cast<const unsigned int*>(
        xwb + (((long)r * N_NODES + s) << 7) + 2 * lane);
    acc0 += cf * b2f((ushort_t)(pk & 0xFFFF));
    acc1 += cf * b2f((ushort_t)(pk >> 16));
  }
  if (xb_out) {
    unsigned int po = ((unsigned int)f2b(acc1) << 16) | (unsigned int)f2b(acc0);
    *reinterpret_cast<unsigned int*>(xb_out + ((long)d << 7) + 2 * lane) = po;
  }
  if (fout) {
    *reinterpret_cast<float2*>(fout + ((long)d << 7) + 2 * lane) =
        make_float2(acc0, acc1);
  }
}

__global__ void final_linear(const float* __restrict__ x, const float* __restrict__ Wc,
                             const float* __restrict__ bc, float* __restrict__ out) {
  __shared__ float wcs[4 * 384];
  for (int t = threadIdx.x; t < 4 * 384; t += blockDim.x) wcs[t] = Wc[t];
  __syncthreads();
  int i = blockIdx.x * blockDim.x + threadIdx.x;
  if (i >= NPV) return;
  float acc[4] = {0.f, 0.f, 0.f, 0.f};
  for (int v = 0; v < 3; ++v) {
    const float* xr = x + ((long)v * NPV + i) * 128;
    for (int c = 0; c < 128; c += 4) {
      float4 xv = *reinterpret_cast<const float4*>(xr + c);
#pragma unroll
      for (int l = 0; l < 4; ++l) {
        const float* w = wcs + l * 384 + v * 128 + c;
        acc[l] += xv.x * w[0] + xv.y * w[1] + xv.z * w[2] + xv.w * w[3];
      }
    }
  }
#pragma unroll
  for (int l = 0; l < 4; ++l) out[(long)i * 4 + l] = acc[l] + bc[l];
}

// ---------------------------------------------------------------------------
static void run_layer(const ushort_t* xb_in, ushort_t* xb_out, float* fout,
                      const float* basis, const float* comp, const float* q,
                      const float* k, ushort_t* xwb, ushort_t* wTb, float* ai,
                      float* aj, float* coef, const int* rstart, const int* recs,
                      hipStream_t stream) {
  compute_wT_b<<<(R_REL * 128 * 128 + 255) / 256, 256, 0, stream>>>(comp, basis, wTb);
  mfma_gemm_nt<false, true><<<dim3(N_NODES / 64, 1, R_REL), 256, 0, stream>>>(
      xb_in, wTb, nullptr, xwb, 128, 128, 128 * 128, (long)N_NODES * 128,
      q, k, ai, aj);
  seg_softmax<<<(NK + 255) / 256, 256, 0, stream>>>(rstart, recs, ai, aj, coef);
  fused_agg<<<N_NODES / 4, 256, 0, stream>>>(rstart, recs, coef, xwb, xb_out, fout);
}

extern "C" void kernel_launch(void* const* d_in, const int* in_sizes, int n_in,
                              void* d_out, int out_size, void* d_ws, size_t ws_size,
                              hipStream_t stream) {
  const float* x0 = (const float*)d_in[0];
  const float* x1 = (const float*)d_in[1];
  const float* x2 = (const float*)d_in[2];
  const int* edge_index = (const int*)d_in[3];
  const int* edge_type = (const int*)d_in[4];
  const float* Wp0 = (const float*)d_in[5];
  const float* bp0 = (const float*)d_in[6];
  const float* Wp1 = (const float*)d_in[7];
  const float* bp1 = (const float*)d_in[8];
  const float* Wp2 = (const float*)d_in[9];
  const float* bp2 = (const float*)d_in[10];
  const float* basis0 = (const float*)d_in[11];
  const float* comp0 = (const float*)d_in[12];
  const float* q0 = (const float*)d_in[13];
  const float* k0 = (const float*)d_in[14];
  const float* basis1 = (const float*)d_in[15];
  const float* comp1 = (const float*)d_in[16];
  const float* q1 = (const float*)d_in[17];
  const float* k1 = (const float*)d_in[18];
  const float* Wc = (const float*)d_in[19];
  const float* bc = (const float*)d_in[20];

  const int* src = edge_index;
  const int* dst = edge_index + E_EDGES;

  // ---- workspace layout ----
  char* w = (char*)d_ws;
  auto alloc = [&](long bytes) {
    char* p = w;
    w += (bytes + 255) & ~255L;
    return p;
  };
  ushort_t* xbA  = (ushort_t*)alloc((long)NX * 2);
  ushort_t* xbB  = (ushort_t*)alloc((long)NX * 2);
  ushort_t* xwb  = (ushort_t*)alloc(9L * NPV * 128 * 4);  // aliased: Ppart (f32) then xwb (bf16)
  ushort_t* wTb  = (ushort_t*)alloc((long)R_REL * 128 * 128 * 2);
  ushort_t* padW = (ushort_t*)alloc(3L * 128 * WPAD * 2); // padded bf16 proj weights
  float* Cacc    = (float*)alloc((long)NX * 4);
  float* ai      = (float*)alloc((long)R_REL * N_NODES * 4 * 4);
  float* aj      = (float*)alloc((long)R_REL * N_NODES * 4 * 4);
  float* coef    = (float*)alloc((long)HEADS * E_EDGES * 4);
  int* cnt       = (int*)alloc((long)NK * 4);
  int* cursor    = (int*)alloc((long)NK * 4);
  int* rstart    = (int*)alloc((long)(NK + 1) * 4);
  int* recs      = (int*)alloc((long)E_EDGES * 4);
  int* blockSums = (int*)alloc((long)SCAN_BLOCKS * 4);
  float* Ppart   = (float*)xwb;  // alias: projection partials die before xwb is written

  // ---- projection weights -> padded bf16 (tiny; once)
  cvt_pad_bf16<<<128, 256, 0, stream>>>(Wp0, padW + 0L * 128 * WPAD, 128, 2000, WPAD);
  cvt_pad_bf16<<<128, 256, 0, stream>>>(Wp1, padW + 1L * 128 * WPAD, 128, 1500, WPAD);
  cvt_pad_bf16<<<128, 256, 0, stream>>>(Wp2, padW + 2L * 128 * WPAD, 128, 500, WPAD);

  // ---- projections: async-DMA split-K (no atomics) -> partials -> reduce
  gemm_proj_split<<<dim3(NPV / 64, 9), 256, 0, stream>>>(
      x0, x1, x2, padW, Ppart);
  proj_reduce<<<(N_NODES * 16 + 255) / 256, 256, 0, stream>>>(
      Ppart, bp0, bp1, bp2, xbA);

  // ---- CSR build keyed by (dst,rel) (once; shared by both layers)
  fill_f32<<<96, 256, 0, stream>>>((float*)cnt, 2L * NK, 0.f);  // cnt+cursor adjacent
  count_key<<<E_EDGES / 256, 256, 0, stream>>>(dst, edge_type, cnt, E_EDGES);
  scan_block<<<SCAN_BLOCKS, 256, 0, stream>>>(cnt, rstart, blockSums);
  scan_sums<<<1, SCAN_BLOCKS, 0, stream>>>(blockSums);
  add_offsets<<<SCAN_BLOCKS, 256, 0, stream>>>(rstart, blockSums);
  scatter_edges<<<E_EDGES / 256, 256, 0, stream>>>(src, dst, edge_type, rstart,
                                                   cursor, recs, E_EDGES);

  // ---- layer 0: xbA -> xbB (bf16)
  run_layer(xbA, xbB, nullptr, basis0, comp0, q0, k0, xwb, wTb, ai, aj, coef,
            rstart, recs, stream);
  // ---- layer 1: xbB -> Cacc (f32 only)
  run_layer(xbB, nullptr, Cacc, basis1, comp1, q1, k1, xwb, wTb, ai, aj, coef,
            rstart, recs, stream);

  final_linear<<<(NPV + 255) / 256, 256, 0, stream>>>(Cacc, Wc, bc, (float*)d_out);
}

// Round 16
// 278.283 us; speedup vs baseline: 1.0158x; 1.0017x over previous
//
#include <hip/hip_runtime.h>
#include <hip/hip_bf16.h>
#include <math.h>

#define N_NODES 24576
#define NPV 8192
#define E_EDGES 393216
#define R_REL 6
#define B_BASES 8
#define HEADS 4
#define NEG_SLOPE 0.2f
#define NX (N_NODES * 128)
#define NK (N_NODES * R_REL)
#define SCAN_BLOCKS (NK / 256)  // 576
#define WPAD 2048               // padded K stride for projection weights (bf16)

typedef unsigned short ushort_t;
using short8 = __attribute__((ext_vector_type(8))) short;
using f32x4 = __attribute__((ext_vector_type(4))) float;

__device__ __forceinline__ float lrelu(float x) { return x >= 0.f ? x : NEG_SLOPE * x; }
__device__ __forceinline__ float b2f(ushort_t u) {
  unsigned int v = ((unsigned int)u) << 16;
  float f;
  __builtin_memcpy(&f, &v, 4);
  return f;
}
__device__ __forceinline__ ushort_t f2b(float f) {
  __hip_bfloat16 h = __float2bfloat16(f);
  ushort_t u;
  __builtin_memcpy(&u, &h, 2);
  return u;
}

// ---------------------------------------------------------------------------
// cvt_pad: f32 [M,K] -> bf16 [M,Kp], zero-padded (used for proj weights).
// ---------------------------------------------------------------------------
__global__ void cvt_pad_bf16(const float* __restrict__ in, ushort_t* __restrict__ out,
                             int M, int K, int Kp) {
  int kp8 = Kp >> 3;
  int total = M * kp8;
  for (int t = blockIdx.x * blockDim.x + threadIdx.x; t < total;
       t += gridDim.x * blockDim.x) {
    int row = t / kp8;
    int c0 = (t - row * kp8) * 8;
    short8 o;
    if (c0 + 7 < K) {
      const float4 a = *reinterpret_cast<const float4*>(in + (long)row * K + c0);
      const float4 b = *reinterpret_cast<const float4*>(in + (long)row * K + c0 + 4);
      o[0] = (short)f2b(a.x); o[1] = (short)f2b(a.y);
      o[2] = (short)f2b(a.z); o[3] = (short)f2b(a.w);
      o[4] = (short)f2b(b.x); o[5] = (short)f2b(b.y);
      o[6] = (short)f2b(b.z); o[7] = (short)f2b(b.w);
    } else {
#pragma unroll
      for (int j = 0; j < 8; ++j) {
        int c = c0 + j;
        float v = (c < K) ? in[(long)row * K + c] : 0.f;
        o[j] = (short)f2b(v);
      }
    }
    *reinterpret_cast<short8*>(out + (long)row * Kp + c0) = o;
  }
}

// ---------------------------------------------------------------------------
// gemm_proj_split: split-K projection via global_load_lds, BM=32 for grid
// parallelism (r13 was grid-limited at 576 blocks / 30% occupancy; this is
// 2304 blocks). W pre-converted padded bf16 (DMA, L2-resident re-reads --
// r11's BM=32 failure was redundant f32 W cvt, which no longer exists).
// A staged raw f32 into LDS; fragment cvt after ds_read. grid (NPV/32, 9).
// ---------------------------------------------------------------------------
__global__ __launch_bounds__(256) void gemm_proj_split(
    const float* __restrict__ x0, const float* __restrict__ x1,
    const float* __restrict__ x2, const ushort_t* __restrict__ wb,
    float* __restrict__ Ppart) {
  __shared__ __align__(16) float Af[32 * 64];      // 8KB f32 A tile
  __shared__ __align__(16) ushort_t Ws[128 * 64];  // 16KB bf16 W tile
  const int z = blockIdx.y;
  const float* A;
  const ushort_t* W;
  int K, kstart, kend;
  if (z < 4) {
    A = x0; W = wb; K = 2000; kstart = z * 512;
  } else if (z < 7) {
    A = x1; W = wb + 128L * WPAD; K = 1500; kstart = (z - 4) * 512;
  } else {
    A = x2; W = wb + 256L * WPAD; K = 500; kstart = (z - 7) * 256;
  }
  kend = kstart + ((z < 7) ? 512 : 256);
  if (kend > K) kend = K;
  const int nfull = (kend - kstart) >> 6;
  const int tail = (kend - kstart) & 63;
  const int nsteps = nfull + (tail ? 1 : 0);

  const int tid = threadIdx.x;
  const int wave = tid >> 6, lane = tid & 63;
  const int m0 = blockIdx.x * 32;
  const int wrow = (wave & 1) * 16;   // wave's 16-row strip of the 32-row tile
  const int wcol = (wave >> 1) * 64;  // wave's 64-col strip

  f32x4 acc[4];
#pragma unroll
  for (int n = 0; n < 4; ++n) acc[n] = (f32x4){0.f, 0.f, 0.f, 0.f};

  for (int step = 0; step < nsteps; ++step) {
    const int k0 = kstart + (step << 6);
    __syncthreads();
    if (step < nfull) {
      // A: 2 f32 16B-chunks per thread, async DMA, source-swizzled
#pragma unroll
      for (int q = 0; q < 2; ++q) {
        int s = q * 256 + tid;
        int row = s >> 4, ch = s & 15;
        int sch = ch ^ (row & 15);
        const float* g = A + (long)(m0 + row) * K + k0 + sch * 4;
        __builtin_amdgcn_global_load_lds(
            (const __attribute__((address_space(1))) unsigned int*)g,
            (__attribute__((address_space(3))) unsigned int*)(Af + s * 4), 16, 0, 0);
      }
    } else {
      // tail: reg-stage A with zero guard (kend == K here by construction)
#pragma unroll
      for (int q = 0; q < 2; ++q) {
        int s = q * 256 + tid;
        int row = s >> 4, ch = s & 15;
        int sch = ch ^ (row & 15);
        int gk = k0 + sch * 4;
        const float* gp = A + (long)(m0 + row) * K + gk;
        float4 v = make_float4(0.f, 0.f, 0.f, 0.f);
#pragma unroll
        for (int j = 0; j < 4; ++j)
          if (gk + j < kend) (&v.x)[j] = gp[j];
        *reinterpret_cast<float4*>(Af + s * 4) = v;
      }
    }
    // W: 4 bf16 16B-chunks per thread, async DMA (padded -> always safe)
#pragma unroll
    for (int q = 0; q < 4; ++q) {
      int s = q * 256 + tid;
      int row = s >> 3, ch = s & 7;
      int sch = ch ^ (row & 7);
      const ushort_t* g = W + (long)row * WPAD + k0 + sch * 8;
      __builtin_amdgcn_global_load_lds(
          (const __attribute__((address_space(1))) unsigned int*)g,
          (__attribute__((address_space(3))) unsigned int*)(Ws + s * 8), 16, 0, 0);
    }
    __syncthreads();
#pragma unroll
    for (int kk = 0; kk < 2; ++kk) {
      const int arow = wrow + (lane & 15);
      const int t = kk * 4 + (lane >> 4);
      const int sc0 = (2 * t) ^ (arow & 15);
      const int sc1 = (2 * t + 1) ^ (arow & 15);
      f32x4 a0 = *reinterpret_cast<const f32x4*>(Af + arow * 64 + sc0 * 4);
      f32x4 a1 = *reinterpret_cast<const f32x4*>(Af + arow * 64 + sc1 * 4);
      short8 afrag;
      afrag[0] = (short)f2b(a0[0]); afrag[1] = (short)f2b(a0[1]);
      afrag[2] = (short)f2b(a0[2]); afrag[3] = (short)f2b(a0[3]);
      afrag[4] = (short)f2b(a1[0]); afrag[5] = (short)f2b(a1[1]);
      afrag[6] = (short)f2b(a1[2]); afrag[7] = (short)f2b(a1[3]);
#pragma unroll
      for (int n = 0; n < 4; ++n) {
        const int brow = wcol + n * 16 + (lane & 15);
        const int bch = t ^ (brow & 7);
        short8 bfrag = *reinterpret_cast<const short8*>(Ws + brow * 64 + bch * 8);
        acc[n] = __builtin_amdgcn_mfma_f32_16x16x32_bf16(afrag, bfrag, acc[n], 0, 0, 0);
      }
    }
  }
  const int rbase = m0 + wrow + (lane >> 4) * 4;
  const int cb = lane & 15;
  float* out = Ppart + (long)z * NPV * 128;
#pragma unroll
  for (int n = 0; n < 4; ++n) {
    int col = wcol + n * 16 + cb;
#pragma unroll
    for (int r = 0; r < 4; ++r)
      out[(long)(rbase + r) * 128 + col] = acc[n][r];
  }
}

// proj_reduce: xb[n, c] = bf16(relu(sum_z Ppart[z][m, c] + bias_v[c]))
__global__ __launch_bounds__(256) void proj_reduce(
    const float* __restrict__ Ppart, const float* __restrict__ b0,
    const float* __restrict__ b1, const float* __restrict__ b2,
    ushort_t* __restrict__ xb) {
  int t = blockIdx.x * blockDim.x + threadIdx.x;
  if (t >= N_NODES * 16) return;
  int n = t >> 4, c0 = (t & 15) * 8;
  int v = n >> 13, m = n & (NPV - 1);
  int zb, zc;
  const float* bias;
  if (v == 0) { zb = 0; zc = 4; bias = b0; }
  else if (v == 1) { zb = 4; zc = 3; bias = b1; }
  else { zb = 7; zc = 2; bias = b2; }
  float s[8];
#pragma unroll
  for (int j = 0; j < 8; ++j) s[j] = bias[c0 + j];
  for (int zz = 0; zz < zc; ++zz) {
    const float* p = Ppart + ((long)(zb + zz) * NPV + m) * 128 + c0;
    float4 a = *reinterpret_cast<const float4*>(p);
    float4 b = *reinterpret_cast<const float4*>(p + 4);
    s[0] += a.x; s[1] += a.y; s[2] += a.z; s[3] += a.w;
    s[4] += b.x; s[5] += b.y; s[6] += b.z; s[7] += b.w;
  }
  short8 o;
#pragma unroll
  for (int j = 0; j < 8; ++j) {
    float vv = s[j] > 0.f ? s[j] : 0.f;
    o[j] = (short)f2b(vv);
  }
  *reinterpret_cast<short8*>(xb + (long)n * 128 + c0) = o;
}

// ---------------------------------------------------------------------------
// xw GEMM (r13 verbatim, proven): xwb[r][M,128] = bf16(xb @ w_r^T) + fused
// ai/aj tables from the f32 accumulators.
// ---------------------------------------------------------------------------
template <bool SPLIT, bool TABLES>
__global__ __launch_bounds__(256) void mfma_gemm_nt(
    const ushort_t* __restrict__ A, const ushort_t* __restrict__ W,
    float* __restrict__ Cacc, ushort_t* __restrict__ Cb,
    int Kp, int kChunk, long strideW, long strideCz,
    const float* __restrict__ qt, const float* __restrict__ kt,
    float* __restrict__ ai, float* __restrict__ aj) {
  __shared__ __align__(16) ushort_t As[64 * 64];
  __shared__ __align__(16) ushort_t Ws[128 * 64];
  const int tid = threadIdx.x;
  const int wave = tid >> 6, lane = tid & 63;
  const int m0 = blockIdx.x * 64;
  const int kbase = blockIdx.y * kChunk;
  const ushort_t* Wz = W + (long)blockIdx.z * strideW;

  f32x4 acc[8];
#pragma unroll
  for (int n = 0; n < 8; ++n) acc[n] = (f32x4){0.f, 0.f, 0.f, 0.f};

  for (int k0 = kbase; k0 < kbase + kChunk; k0 += 64) {
    __syncthreads();
#pragma unroll
    for (int q = 0; q < 2; ++q) {
      int s = q * 256 + tid;
      int row = s >> 3, ch = s & 7;
      int sch = ch ^ (row & 7);
      const ushort_t* g = A + (long)(m0 + row) * Kp + k0 + sch * 8;
      __builtin_amdgcn_global_load_lds(
          (const __attribute__((address_space(1))) unsigned int*)g,
          (__attribute__((address_space(3))) unsigned int*)(As + s * 8), 16, 0, 0);
    }
#pragma unroll
    for (int q = 0; q < 4; ++q) {
      int s = q * 256 + tid;
      int row = s >> 3, ch = s & 7;
      int sch = ch ^ (row & 7);
      const ushort_t* g = Wz + (long)row * Kp + k0 + sch * 8;
      __builtin_amdgcn_global_load_lds(
          (const __attribute__((address_space(1))) unsigned int*)g,
          (__attribute__((address_space(3))) unsigned int*)(Ws + s * 8), 16, 0, 0);
    }
    __syncthreads();
#pragma unroll
    for (int kk = 0; kk < 2; ++kk) {
      const int arow = wave * 16 + (lane & 15);
      const int ach = (kk * 4 + (lane >> 4)) ^ (arow & 7);
      short8 afrag = *reinterpret_cast<const short8*>(As + arow * 64 + ach * 8);
#pragma unroll
      for (int n = 0; n < 8; ++n) {
        const int brow = n * 16 + (lane & 15);
        const int bch = (kk * 4 + (lane >> 4)) ^ (brow & 7);
        short8 bfrag = *reinterpret_cast<const short8*>(Ws + brow * 64 + bch * 8);
        acc[n] = __builtin_amdgcn_mfma_f32_16x16x32_bf16(afrag, bfrag, acc[n], 0, 0, 0);
      }
    }
  }
  const int rbase = m0 + wave * 16 + (lane >> 4) * 4;
  const int cb = lane & 15;
  if (SPLIT) {
#pragma unroll
    for (int n = 0; n < 8; ++n) {
      int col = n * 16 + cb;
#pragma unroll
      for (int r = 0; r < 4; ++r)
        atomicAdd(&Cacc[(long)(rbase + r) * 128 + col], acc[n][r]);
    }
  } else {
    ushort_t* Cz = Cb + (long)blockIdx.z * strideCz;
#pragma unroll
    for (int n = 0; n < 8; ++n) {
      int col = n * 16 + cb;
#pragma unroll
      for (int r = 0; r < 4; ++r)
        Cz[(long)(rbase + r) * 128 + col] = f2b(acc[n][r]);
    }
  }
  if (TABLES) {
    float aq[4][4], ak[4][4];
#pragma unroll
    for (int r = 0; r < 4; ++r)
#pragma unroll
      for (int h = 0; h < 4; ++h) { aq[r][h] = 0.f; ak[r][h] = 0.f; }
#pragma unroll
    for (int n = 0; n < 8; ++n) {
      int col = n * 16 + cb;
      float4 qv = *reinterpret_cast<const float4*>(qt + (long)col * 4);
      float4 kv = *reinterpret_cast<const float4*>(kt + (long)col * 4);
#pragma unroll
      for (int r = 0; r < 4; ++r) {
        float x = acc[n][r];
        aq[r][0] += x * qv.x; aq[r][1] += x * qv.y;
        aq[r][2] += x * qv.z; aq[r][3] += x * qv.w;
        ak[r][0] += x * kv.x; ak[r][1] += x * kv.y;
        ak[r][2] += x * kv.z; ak[r][3] += x * kv.w;
      }
    }
#pragma unroll
    for (int mk = 1; mk < 16; mk <<= 1) {
#pragma unroll
      for (int r = 0; r < 4; ++r)
#pragma unroll
        for (int h = 0; h < 4; ++h) {
          aq[r][h] += __shfl_xor(aq[r][h], mk);
          ak[r][h] += __shfl_xor(ak[r][h], mk);
        }
    }
    int rr = cb >> 2, hh = cb & 3;
    long row = (long)blockIdx.z * N_NODES + rbase + rr;
    ai[row * 4 + hh] = aq[rr][hh];
    aj[row * 4 + hh] = ak[rr][hh];
  }
}

// ---------------------------------------------------------------------------
__global__ void fill_f32(float* __restrict__ p, long n, float v) {
  long i = blockIdx.x * (long)blockDim.x + threadIdx.x;
  long stride = (long)gridDim.x * blockDim.x;
  for (; i < n; i += stride) p[i] = v;
}

// wTb[r,o,i] = bf16( sum_b comp[r,b] * basis[b,i,o] )
__global__ void compute_wT_b(const float* __restrict__ comp,
                             const float* __restrict__ basis,
                             ushort_t* __restrict__ wTb) {
  int idx = blockIdx.x * blockDim.x + threadIdx.x;
  if (idx >= R_REL * 128 * 128) return;
  int r = idx >> 14;
  int rem = idx & 16383;
  int o = rem >> 7;
  int i = rem & 127;
  float s = 0.f;
#pragma unroll
  for (int b = 0; b < B_BASES; ++b)
    s += comp[r * B_BASES + b] * basis[((b << 7) + i) * 128 + o];
  wTb[((long)(r << 7) + o) * 128 + i] = f2b(s);
}

// ---------------------------------------------------------------------------
// CSR build keyed by (dst*6 + rel): count -> hierarchical scan -> scatter.
// ---------------------------------------------------------------------------
__global__ void count_key(const int* __restrict__ dst, const int* __restrict__ et,
                          int* __restrict__ cnt, int E) {
  int e = blockIdx.x * blockDim.x + threadIdx.x;
  if (e < E) atomicAdd(&cnt[dst[e] * R_REL + et[e]], 1);
}

__global__ __launch_bounds__(256) void scan_block(const int* __restrict__ cnt,
                                                  int* __restrict__ start,
                                                  int* __restrict__ blockSums) {
  __shared__ int sm[256];
  const int t = threadIdx.x;
  const int i = blockIdx.x * 256 + t;
  int v = cnt[i];
  sm[t] = v;
  __syncthreads();
  for (int off = 1; off < 256; off <<= 1) {
    int u = (t >= off) ? sm[t - off] : 0;
    __syncthreads();
    sm[t] += u;
    __syncthreads();
  }
  start[i] = sm[t] - v;  // exclusive
  if (t == 255) blockSums[blockIdx.x] = sm[255];
}

__global__ __launch_bounds__(SCAN_BLOCKS) void scan_sums(int* __restrict__ blockSums) {
  __shared__ int sm[SCAN_BLOCKS];
  const int t = threadIdx.x;
  int v = blockSums[t];
  sm[t] = v;
  __syncthreads();
  for (int off = 1; off < SCAN_BLOCKS; off <<= 1) {
    int u = (t >= off) ? sm[t - off] : 0;
    __syncthreads();
    sm[t] += u;
    __syncthreads();
  }
  blockSums[t] = sm[t] - v;  // exclusive
}

__global__ __launch_bounds__(256) void add_offsets(int* __restrict__ start,
                                                   const int* __restrict__ blockSums) {
  int i = blockIdx.x * 256 + threadIdx.x;
  start[i] += blockSums[blockIdx.x];
  if (i == 0) start[NK] = E_EDGES;
}

__global__ void scatter_edges(const int* __restrict__ src, const int* __restrict__ dst,
                              const int* __restrict__ et, const int* __restrict__ start,
                              int* __restrict__ cursor, int* __restrict__ recs, int E) {
  int e = blockIdx.x * blockDim.x + threadIdx.x;
  if (e >= E) return;
  int key = dst[e] * R_REL + et[e];
  int pos = start[key] + atomicAdd(&cursor[key], 1);
  recs[pos] = src[e] | (et[e] << 16);
}

// ---------------------------------------------------------------------------
// seg_softmax: one thread per (dst,rel) segment -> per-edge coef[h*E + pos].
// ---------------------------------------------------------------------------
__global__ __launch_bounds__(256) void seg_softmax(
    const int* __restrict__ rstart, const int* __restrict__ recs,
    const float* __restrict__ ai, const float* __restrict__ aj,
    float* __restrict__ coef) {
  int seg = blockIdx.x * blockDim.x + threadIdx.x;
  if (seg >= NK) return;
  int p0 = rstart[seg], p1 = rstart[seg + 1];
  if (p0 == p1) return;
  int d = seg / R_REL, r = seg - d * R_REL;
  float4 av = *reinterpret_cast<const float4*>(ai + ((long)r * N_NODES + d) * 4);
  float degf = (float)(rstart[(d + 1) * R_REL] - rstart[d * R_REL]);
  float m[4] = {-INFINITY, -INFINITY, -INFINITY, -INFINITY};
  float sum[4] = {0.f, 0.f, 0.f, 0.f};
  for (int p = p0; p < p1; ++p) {
    int s = recs[p] & 0xFFFF;
    float4 bv = *reinterpret_cast<const float4*>(aj + ((long)r * N_NODES + s) * 4);
    float al[4] = {lrelu(av.x + bv.x), lrelu(av.y + bv.y),
                   lrelu(av.z + bv.z), lrelu(av.w + bv.w)};
#pragma unroll
    for (int h = 0; h < 4; ++h) {
      float nm = fmaxf(m[h], al[h]);
      sum[h] = sum[h] * __expf(m[h] - nm) + __expf(al[h] - nm);
      m[h] = nm;
    }
  }
  float rs[4];
#pragma unroll
  for (int h = 0; h < 4; ++h) rs[h] = degf / (sum[h] + 1e-16f);
  for (int p = p0; p < p1; ++p) {
    int s = recs[p] & 0xFFFF;
    float4 bv = *reinterpret_cast<const float4*>(aj + ((long)r * N_NODES + s) * 4);
    float al[4] = {lrelu(av.x + bv.x), lrelu(av.y + bv.y),
                   lrelu(av.z + bv.z), lrelu(av.w + bv.w)};
#pragma unroll
    for (int h = 0; h < 4; ++h)
      coef[(long)h * E_EDGES + p] = __expf(al[h] - m[h]) * rs[h];
  }
}

// ---------------------------------------------------------------------------
// fused_agg: one wave per dst node; pure gather-accumulate over xwb.
// ---------------------------------------------------------------------------
__global__ __launch_bounds__(256) void fused_agg(
    const int* __restrict__ rstart, const int* __restrict__ recs,
    const float* __restrict__ coef, const ushort_t* __restrict__ xwb,
    ushort_t* __restrict__ xb_out, float* __restrict__ fout) {
  const int wave = threadIdx.x >> 6, lane = threadIdx.x & 63;
  const int d = blockIdx.x * 4 + wave;
  const int s0 = rstart[d * R_REL], s1 = rstart[(d + 1) * R_REL];
  const float* cfp = coef + (long)(lane >> 4) * E_EDGES;
  float acc0 = 0.f, acc1 = 0.f;
#pragma unroll 4
  for (int pos = s0; pos < s1; ++pos) {
    int rec = recs[pos];
    float cf = cfp[pos];
    int s = rec & 0xFFFF, r = rec >> 16;
    unsigned int pk = *reinterpret_cast<const unsigned int*>(
        xwb + (((long)r * N_NODES + s) << 7) + 2 * lane);
    acc0 += cf * b2f((ushort_t)(pk & 0xFFFF));
    acc1 += cf * b2f((ushort_t)(pk >> 16));
  }
  if (xb_out) {
    unsigned int po = ((unsigned int)f2b(acc1) << 16) | (unsigned int)f2b(acc0);
    *reinterpret_cast<unsigned int*>(xb_out + ((long)d << 7) + 2 * lane) = po;
  }
  if (fout) {
    *reinterpret_cast<float2*>(fout + ((long)d << 7) + 2 * lane) =
        make_float2(acc0, acc1);
  }
}

__global__ void final_linear(const float* __restrict__ x, const float* __restrict__ Wc,
                             const float* __restrict__ bc, float* __restrict__ out) {
  __shared__ float wcs[4 * 384];
  for (int t = threadIdx.x; t < 4 * 384; t += blockDim.x) wcs[t] = Wc[t];
  __syncthreads();
  int i = blockIdx.x * blockDim.x + threadIdx.x;
  if (i >= NPV) return;
  float acc[4] = {0.f, 0.f, 0.f, 0.f};
  for (int v = 0; v < 3; ++v) {
    const float* xr = x + ((long)v * NPV + i) * 128;
    for (int c = 0; c < 128; c += 4) {
      float4 xv = *reinterpret_cast<const float4*>(xr + c);
#pragma unroll
      for (int l = 0; l < 4; ++l) {
        const float* w = wcs + l * 384 + v * 128 + c;
        acc[l] += xv.x * w[0] + xv.y * w[1] + xv.z * w[2] + xv.w * w[3];
      }
    }
  }
#pragma unroll
  for (int l = 0; l < 4; ++l) out[(long)i * 4 + l] = acc[l] + bc[l];
}

// ---------------------------------------------------------------------------
static void run_layer(const ushort_t* xb_in, ushort_t* xb_out, float* fout,
                      const float* basis, const float* comp, const float* q,
                      const float* k, ushort_t* xwb, ushort_t* wTb, float* ai,
                      float* aj, float* coef, const int* rstart, const int* recs,
                      hipStream_t stream) {
  compute_wT_b<<<(R_REL * 128 * 128 + 255) / 256, 256, 0, stream>>>(comp, basis, wTb);
  mfma_gemm_nt<false, true><<<dim3(N_NODES / 64, 1, R_REL), 256, 0, stream>>>(
      xb_in, wTb, nullptr, xwb, 128, 128, 128 * 128, (long)N_NODES * 128,
      q, k, ai, aj);
  seg_softmax<<<(NK + 255) / 256, 256, 0, stream>>>(rstart, recs, ai, aj, coef);
  fused_agg<<<N_NODES / 4, 256, 0, stream>>>(rstart, recs, coef, xwb, xb_out, fout);
}

extern "C" void kernel_launch(void* const* d_in, const int* in_sizes, int n_in,
                              void* d_out, int out_size, void* d_ws, size_t ws_size,
                              hipStream_t stream) {
  const float* x0 = (const float*)d_in[0];
  const float* x1 = (const float*)d_in[1];
  const float* x2 = (const float*)d_in[2];
  const int* edge_index = (const int*)d_in[3];
  const int* edge_type = (const int*)d_in[4];
  const float* Wp0 = (const float*)d_in[5];
  const float* bp0 = (const float*)d_in[6];
  const float* Wp1 = (const float*)d_in[7];
  const float* bp1 = (const float*)d_in[8];
  const float* Wp2 = (const float*)d_in[9];
  const float* bp2 = (const float*)d_in[10];
  const float* basis0 = (const float*)d_in[11];
  const float* comp0 = (const float*)d_in[12];
  const float* q0 = (const float*)d_in[13];
  const float* k0 = (const float*)d_in[14];
  const float* basis1 = (const float*)d_in[15];
  const float* comp1 = (const float*)d_in[16];
  const float* q1 = (const float*)d_in[17];
  const float* k1 = (const float*)d_in[18];
  const float* Wc = (const float*)d_in[19];
  const float* bc = (const float*)d_in[20];

  const int* src = edge_index;
  const int* dst = edge_index + E_EDGES;

  // ---- workspace layout ----
  char* w = (char*)d_ws;
  auto alloc = [&](long bytes) {
    char* p = w;
    w += (bytes + 255) & ~255L;
    return p;
  };
  ushort_t* xbA  = (ushort_t*)alloc((long)NX * 2);
  ushort_t* xbB  = (ushort_t*)alloc((long)NX * 2);
  ushort_t* xwb  = (ushort_t*)alloc(9L * NPV * 128 * 4);  // aliased: Ppart (f32) then xwb (bf16)
  ushort_t* wTb  = (ushort_t*)alloc((long)R_REL * 128 * 128 * 2);
  ushort_t* padW = (ushort_t*)alloc(3L * 128 * WPAD * 2); // padded bf16 proj weights
  float* Cacc    = (float*)alloc((long)NX * 4);
  float* ai      = (float*)alloc((long)R_REL * N_NODES * 4 * 4);
  float* aj      = (float*)alloc((long)R_REL * N_NODES * 4 * 4);
  float* coef    = (float*)alloc((long)HEADS * E_EDGES * 4);
  int* cnt       = (int*)alloc((long)NK * 4);
  int* cursor    = (int*)alloc((long)NK * 4);
  int* rstart    = (int*)alloc((long)(NK + 1) * 4);
  int* recs      = (int*)alloc((long)E_EDGES * 4);
  int* blockSums = (int*)alloc((long)SCAN_BLOCKS * 4);
  float* Ppart   = (float*)xwb;  // alias: projection partials die before xwb is written

  // ---- projection weights -> padded bf16 (tiny; once)
  cvt_pad_bf16<<<128, 256, 0, stream>>>(Wp0, padW + 0L * 128 * WPAD, 128, 2000, WPAD);
  cvt_pad_bf16<<<128, 256, 0, stream>>>(Wp1, padW + 1L * 128 * WPAD, 128, 1500, WPAD);
  cvt_pad_bf16<<<128, 256, 0, stream>>>(Wp2, padW + 2L * 128 * WPAD, 128, 500, WPAD);

  // ---- projections: async-DMA split-K, BM=32 (2304 blocks) -> reduce
  gemm_proj_split<<<dim3(NPV / 32, 9), 256, 0, stream>>>(
      x0, x1, x2, padW, Ppart);
  proj_reduce<<<(N_NODES * 16 + 255) / 256, 256, 0, stream>>>(
      Ppart, bp0, bp1, bp2, xbA);

  // ---- CSR build keyed by (dst,rel) (once; shared by both layers)
  fill_f32<<<96, 256, 0, stream>>>((float*)cnt, 2L * NK, 0.f);  // cnt+cursor adjacent
  count_key<<<E_EDGES / 256, 256, 0, stream>>>(dst, edge_type, cnt, E_EDGES);
  scan_block<<<SCAN_BLOCKS, 256, 0, stream>>>(cnt, rstart, blockSums);
  scan_sums<<<1, SCAN_BLOCKS, 0, stream>>>(blockSums);
  add_offsets<<<SCAN_BLOCKS, 256, 0, stream>>>(rstart, blockSums);
  scatter_edges<<<E_EDGES / 256, 256, 0, stream>>>(src, dst, edge_type, rstart,
                                                   cursor, recs, E_EDGES);

  // ---- layer 0: xbA -> xbB (bf16)
  run_layer(xbA, xbB, nullptr, basis0, comp0, q0, k0, xwb, wTb, ai, aj, coef,
            rstart, recs, stream);
  // ---- layer 1: xbB -> Cacc (f32 only)
  run_layer(xbB, nullptr, Cacc, basis1, comp1, q1, k1, xwb, wTb, ai, aj, coef,
            rstart, recs, stream);

  final_linear<<<(NPV + 255) / 256, 256, 0, stream>>>(Cacc, Wc, bc, (float*)d_out);
}

// Round 17
// 275.814 us; speedup vs baseline: 1.0249x; 1.0090x over previous
//
#include <hip/hip_runtime.h>
#include <hip/hip_bf16.h>
#include <math.h>

#define N_NODES 24576
#define NPV 8192
#define E_EDGES 393216
#define R_REL 6
#define B_BASES 8
#define HEADS 4
#define NEG_SLOPE 0.2f
#define NX (N_NODES * 128)
#define NK (N_NODES * R_REL)
#define SCAN_BLOCKS (NK / 256)  // 576
#define WPAD 2048               // padded K stride for projection weights (bf16)

typedef unsigned short ushort_t;
using short8 = __attribute__((ext_vector_type(8))) short;
using f32x4 = __attribute__((ext_vector_type(4))) float;

__device__ __forceinline__ float lrelu(float x) { return x >= 0.f ? x : NEG_SLOPE * x; }
__device__ __forceinline__ float b2f(ushort_t u) {
  unsigned int v = ((unsigned int)u) << 16;
  float f;
  __builtin_memcpy(&f, &v, 4);
  return f;
}
__device__ __forceinline__ ushort_t f2b(float f) {
  __hip_bfloat16 h = __float2bfloat16(f);
  ushort_t u;
  __builtin_memcpy(&u, &h, 2);
  return u;
}

// ---------------------------------------------------------------------------
// cvt_pad: f32 [M,K] -> bf16 [M,Kp], zero-padded (used for proj weights).
// ---------------------------------------------------------------------------
__global__ void cvt_pad_bf16(const float* __restrict__ in, ushort_t* __restrict__ out,
                             int M, int K, int Kp) {
  int kp8 = Kp >> 3;
  int total = M * kp8;
  for (int t = blockIdx.x * blockDim.x + threadIdx.x; t < total;
       t += gridDim.x * blockDim.x) {
    int row = t / kp8;
    int c0 = (t - row * kp8) * 8;
    short8 o;
    if (c0 + 7 < K) {
      const float4 a = *reinterpret_cast<const float4*>(in + (long)row * K + c0);
      const float4 b = *reinterpret_cast<const float4*>(in + (long)row * K + c0 + 4);
      o[0] = (short)f2b(a.x); o[1] = (short)f2b(a.y);
      o[2] = (short)f2b(a.z); o[3] = (short)f2b(a.w);
      o[4] = (short)f2b(b.x); o[5] = (short)f2b(b.y);
      o[6] = (short)f2b(b.z); o[7] = (short)f2b(b.w);
    } else {
#pragma unroll
      for (int j = 0; j < 8; ++j) {
        int c = c0 + j;
        float v = (c < K) ? in[(long)row * K + c] : 0.f;
        o[j] = (short)f2b(v);
      }
    }
    *reinterpret_cast<short8*>(out + (long)row * Kp + c0) = o;
  }
}

// ---------------------------------------------------------------------------
// gemm_proj_full: NO split-K. grid (NPV/32, 3): z = view, full K per block.
// A staged raw f32 via global_load_lds; W pre-converted padded bf16 via DMA.
// Epilogue fuses bias+relu+bf16 store directly into xb (r8-proven pattern)
// -- removes Ppart (37.7MB write+read) and the proj_reduce kernel entirely.
// ---------------------------------------------------------------------------
__global__ __launch_bounds__(256) void gemm_proj_full(
    const float* __restrict__ x0, const float* __restrict__ x1,
    const float* __restrict__ x2, const ushort_t* __restrict__ wb,
    const float* __restrict__ b0, const float* __restrict__ b1,
    const float* __restrict__ b2, ushort_t* __restrict__ xb) {
  __shared__ __align__(16) float Af[32 * 64];      // 8KB f32 A tile
  __shared__ __align__(16) ushort_t Ws[128 * 64];  // 16KB bf16 W tile
  const int z = blockIdx.y;
  const float* A;
  const ushort_t* W;
  const float* bias;
  int K;
  if (z == 0)      { A = x0; W = wb;                 bias = b0; K = 2000; }
  else if (z == 1) { A = x1; W = wb + 128L * WPAD;   bias = b1; K = 1500; }
  else             { A = x2; W = wb + 256L * WPAD;   bias = b2; K = 500; }
  const int nfull = K >> 6;
  const int tail = K & 63;
  const int nsteps = nfull + (tail ? 1 : 0);

  const int tid = threadIdx.x;
  const int wave = tid >> 6, lane = tid & 63;
  const int m0 = blockIdx.x * 32;
  const int wrow = (wave & 1) * 16;   // wave's 16-row strip of the 32-row tile
  const int wcol = (wave >> 1) * 64;  // wave's 64-col strip

  f32x4 acc[4];
#pragma unroll
  for (int n = 0; n < 4; ++n) acc[n] = (f32x4){0.f, 0.f, 0.f, 0.f};

  for (int step = 0; step < nsteps; ++step) {
    const int k0 = step << 6;
    __syncthreads();
    if (step < nfull) {
      // A: 2 f32 16B-chunks per thread, async DMA, source-swizzled
#pragma unroll
      for (int q = 0; q < 2; ++q) {
        int s = q * 256 + tid;
        int row = s >> 4, ch = s & 15;
        int sch = ch ^ (row & 15);
        const float* g = A + (long)(m0 + row) * K + k0 + sch * 4;
        __builtin_amdgcn_global_load_lds(
            (const __attribute__((address_space(1))) unsigned int*)g,
            (__attribute__((address_space(3))) unsigned int*)(Af + s * 4), 16, 0, 0);
      }
    } else {
      // tail: reg-stage A with zero guard
#pragma unroll
      for (int q = 0; q < 2; ++q) {
        int s = q * 256 + tid;
        int row = s >> 4, ch = s & 15;
        int sch = ch ^ (row & 15);
        int gk = k0 + sch * 4;
        const float* gp = A + (long)(m0 + row) * K + gk;
        float4 v = make_float4(0.f, 0.f, 0.f, 0.f);
#pragma unroll
        for (int j = 0; j < 4; ++j)
          if (gk + j < K) (&v.x)[j] = gp[j];
        *reinterpret_cast<float4*>(Af + s * 4) = v;
      }
    }
    // W: 4 bf16 16B-chunks per thread, async DMA (padded -> always safe)
#pragma unroll
    for (int q = 0; q < 4; ++q) {
      int s = q * 256 + tid;
      int row = s >> 3, ch = s & 7;
      int sch = ch ^ (row & 7);
      const ushort_t* g = W + (long)row * WPAD + k0 + sch * 8;
      __builtin_amdgcn_global_load_lds(
          (const __attribute__((address_space(1))) unsigned int*)g,
          (__attribute__((address_space(3))) unsigned int*)(Ws + s * 8), 16, 0, 0);
    }
    __syncthreads();
#pragma unroll
    for (int kk = 0; kk < 2; ++kk) {
      const int arow = wrow + (lane & 15);
      const int t = kk * 4 + (lane >> 4);
      const int sc0 = (2 * t) ^ (arow & 15);
      const int sc1 = (2 * t + 1) ^ (arow & 15);
      f32x4 a0 = *reinterpret_cast<const f32x4*>(Af + arow * 64 + sc0 * 4);
      f32x4 a1 = *reinterpret_cast<const f32x4*>(Af + arow * 64 + sc1 * 4);
      short8 afrag;
      afrag[0] = (short)f2b(a0[0]); afrag[1] = (short)f2b(a0[1]);
      afrag[2] = (short)f2b(a0[2]); afrag[3] = (short)f2b(a0[3]);
      afrag[4] = (short)f2b(a1[0]); afrag[5] = (short)f2b(a1[1]);
      afrag[6] = (short)f2b(a1[2]); afrag[7] = (short)f2b(a1[3]);
#pragma unroll
      for (int n = 0; n < 4; ++n) {
        const int brow = wcol + n * 16 + (lane & 15);
        const int bch = t ^ (brow & 7);
        short8 bfrag = *reinterpret_cast<const short8*>(Ws + brow * 64 + bch * 8);
        acc[n] = __builtin_amdgcn_mfma_f32_16x16x32_bf16(afrag, bfrag, acc[n], 0, 0, 0);
      }
    }
  }
  // fused epilogue: bias + relu + bf16, direct store (r8-proven pattern)
  const int rbase = m0 + wrow + (lane >> 4) * 4;
  const int cb = lane & 15;
  ushort_t* out = xb + (long)z * NPV * 128;
#pragma unroll
  for (int n = 0; n < 4; ++n) {
    int col = wcol + n * 16 + cb;
    float bz = bias[col];
#pragma unroll
    for (int r = 0; r < 4; ++r) {
      float v = acc[n][r] + bz;
      v = v > 0.f ? v : 0.f;
      out[(long)(rbase + r) * 128 + col] = f2b(v);
    }
  }
}

// ---------------------------------------------------------------------------
// xw GEMM (proven): xwb[r][M,128] = bf16(xb @ w_r^T) + fused ai/aj tables.
// ---------------------------------------------------------------------------
template <bool SPLIT, bool TABLES>
__global__ __launch_bounds__(256) void mfma_gemm_nt(
    const ushort_t* __restrict__ A, const ushort_t* __restrict__ W,
    float* __restrict__ Cacc, ushort_t* __restrict__ Cb,
    int Kp, int kChunk, long strideW, long strideCz,
    const float* __restrict__ qt, const float* __restrict__ kt,
    float* __restrict__ ai, float* __restrict__ aj) {
  __shared__ __align__(16) ushort_t As[64 * 64];
  __shared__ __align__(16) ushort_t Ws[128 * 64];
  const int tid = threadIdx.x;
  const int wave = tid >> 6, lane = tid & 63;
  const int m0 = blockIdx.x * 64;
  const int kbase = blockIdx.y * kChunk;
  const ushort_t* Wz = W + (long)blockIdx.z * strideW;

  f32x4 acc[8];
#pragma unroll
  for (int n = 0; n < 8; ++n) acc[n] = (f32x4){0.f, 0.f, 0.f, 0.f};

  for (int k0 = kbase; k0 < kbase + kChunk; k0 += 64) {
    __syncthreads();
#pragma unroll
    for (int q = 0; q < 2; ++q) {
      int s = q * 256 + tid;
      int row = s >> 3, ch = s & 7;
      int sch = ch ^ (row & 7);
      const ushort_t* g = A + (long)(m0 + row) * Kp + k0 + sch * 8;
      __builtin_amdgcn_global_load_lds(
          (const __attribute__((address_space(1))) unsigned int*)g,
          (__attribute__((address_space(3))) unsigned int*)(As + s * 8), 16, 0, 0);
    }
#pragma unroll
    for (int q = 0; q < 4; ++q) {
      int s = q * 256 + tid;
      int row = s >> 3, ch = s & 7;
      int sch = ch ^ (row & 7);
      const ushort_t* g = Wz + (long)row * Kp + k0 + sch * 8;
      __builtin_amdgcn_global_load_lds(
          (const __attribute__((address_space(1))) unsigned int*)g,
          (__attribute__((address_space(3))) unsigned int*)(Ws + s * 8), 16, 0, 0);
    }
    __syncthreads();
#pragma unroll
    for (int kk = 0; kk < 2; ++kk) {
      const int arow = wave * 16 + (lane & 15);
      const int ach = (kk * 4 + (lane >> 4)) ^ (arow & 7);
      short8 afrag = *reinterpret_cast<const short8*>(As + arow * 64 + ach * 8);
#pragma unroll
      for (int n = 0; n < 8; ++n) {
        const int brow = n * 16 + (lane & 15);
        const int bch = (kk * 4 + (lane >> 4)) ^ (brow & 7);
        short8 bfrag = *reinterpret_cast<const short8*>(Ws + brow * 64 + bch * 8);
        acc[n] = __builtin_amdgcn_mfma_f32_16x16x32_bf16(afrag, bfrag, acc[n], 0, 0, 0);
      }
    }
  }
  const int rbase = m0 + wave * 16 + (lane >> 4) * 4;
  const int cb = lane & 15;
  if (SPLIT) {
#pragma unroll
    for (int n = 0; n < 8; ++n) {
      int col = n * 16 + cb;
#pragma unroll
      for (int r = 0; r < 4; ++r)
        atomicAdd(&Cacc[(long)(rbase + r) * 128 + col], acc[n][r]);
    }
  } else {
    ushort_t* Cz = Cb + (long)blockIdx.z * strideCz;
#pragma unroll
    for (int n = 0; n < 8; ++n) {
      int col = n * 16 + cb;
#pragma unroll
      for (int r = 0; r < 4; ++r)
        Cz[(long)(rbase + r) * 128 + col] = f2b(acc[n][r]);
    }
  }
  if (TABLES) {
    float aq[4][4], ak[4][4];
#pragma unroll
    for (int r = 0; r < 4; ++r)
#pragma unroll
      for (int h = 0; h < 4; ++h) { aq[r][h] = 0.f; ak[r][h] = 0.f; }
#pragma unroll
    for (int n = 0; n < 8; ++n) {
      int col = n * 16 + cb;
      float4 qv = *reinterpret_cast<const float4*>(qt + (long)col * 4);
      float4 kv = *reinterpret_cast<const float4*>(kt + (long)col * 4);
#pragma unroll
      for (int r = 0; r < 4; ++r) {
        float x = acc[n][r];
        aq[r][0] += x * qv.x; aq[r][1] += x * qv.y;
        aq[r][2] += x * qv.z; aq[r][3] += x * qv.w;
        ak[r][0] += x * kv.x; ak[r][1] += x * kv.y;
        ak[r][2] += x * kv.z; ak[r][3] += x * kv.w;
      }
    }
#pragma unroll
    for (int mk = 1; mk < 16; mk <<= 1) {
#pragma unroll
      for (int r = 0; r < 4; ++r)
#pragma unroll
        for (int h = 0; h < 4; ++h) {
          aq[r][h] += __shfl_xor(aq[r][h], mk);
          ak[r][h] += __shfl_xor(ak[r][h], mk);
        }
    }
    int rr = cb >> 2, hh = cb & 3;
    long row = (long)blockIdx.z * N_NODES + rbase + rr;
    ai[row * 4 + hh] = aq[rr][hh];
    aj[row * 4 + hh] = ak[rr][hh];
  }
}

// ---------------------------------------------------------------------------
__global__ void fill_f32(float* __restrict__ p, long n, float v) {
  long i = blockIdx.x * (long)blockDim.x + threadIdx.x;
  long stride = (long)gridDim.x * blockDim.x;
  for (; i < n; i += stride) p[i] = v;
}

// wTb[r,o,i] = bf16( sum_b comp[r,b] * basis[b,i,o] )
__global__ void compute_wT_b(const float* __restrict__ comp,
                             const float* __restrict__ basis,
                             ushort_t* __restrict__ wTb) {
  int idx = blockIdx.x * blockDim.x + threadIdx.x;
  if (idx >= R_REL * 128 * 128) return;
  int r = idx >> 14;
  int rem = idx & 16383;
  int o = rem >> 7;
  int i = rem & 127;
  float s = 0.f;
#pragma unroll
  for (int b = 0; b < B_BASES; ++b)
    s += comp[r * B_BASES + b] * basis[((b << 7) + i) * 128 + o];
  wTb[((long)(r << 7) + o) * 128 + i] = f2b(s);
}

// ---------------------------------------------------------------------------
// CSR build keyed by (dst*6 + rel): count -> hierarchical scan -> scatter.
// ---------------------------------------------------------------------------
__global__ void count_key(const int* __restrict__ dst, const int* __restrict__ et,
                          int* __restrict__ cnt, int E) {
  int e = blockIdx.x * blockDim.x + threadIdx.x;
  if (e < E) atomicAdd(&cnt[dst[e] * R_REL + et[e]], 1);
}

__global__ __launch_bounds__(256) void scan_block(const int* __restrict__ cnt,
                                                  int* __restrict__ start,
                                                  int* __restrict__ blockSums) {
  __shared__ int sm[256];
  const int t = threadIdx.x;
  const int i = blockIdx.x * 256 + t;
  int v = cnt[i];
  sm[t] = v;
  __syncthreads();
  for (int off = 1; off < 256; off <<= 1) {
    int u = (t >= off) ? sm[t - off] : 0;
    __syncthreads();
    sm[t] += u;
    __syncthreads();
  }
  start[i] = sm[t] - v;  // exclusive
  if (t == 255) blockSums[blockIdx.x] = sm[255];
}

__global__ __launch_bounds__(SCAN_BLOCKS) void scan_sums(int* __restrict__ blockSums) {
  __shared__ int sm[SCAN_BLOCKS];
  const int t = threadIdx.x;
  int v = blockSums[t];
  sm[t] = v;
  __syncthreads();
  for (int off = 1; off < SCAN_BLOCKS; off <<= 1) {
    int u = (t >= off) ? sm[t - off] : 0;
    __syncthreads();
    sm[t] += u;
    __syncthreads();
  }
  blockSums[t] = sm[t] - v;  // exclusive
}

__global__ __launch_bounds__(256) void add_offsets(int* __restrict__ start,
                                                   const int* __restrict__ blockSums) {
  int i = blockIdx.x * 256 + threadIdx.x;
  start[i] += blockSums[blockIdx.x];
  if (i == 0) start[NK] = E_EDGES;
}

__global__ void scatter_edges(const int* __restrict__ src, const int* __restrict__ dst,
                              const int* __restrict__ et, const int* __restrict__ start,
                              int* __restrict__ cursor, int* __restrict__ recs, int E) {
  int e = blockIdx.x * blockDim.x + threadIdx.x;
  if (e >= E) return;
  int key = dst[e] * R_REL + et[e];
  int pos = start[key] + atomicAdd(&cursor[key], 1);
  recs[pos] = src[e] | (et[e] << 16);
}

// ---------------------------------------------------------------------------
// seg_softmax: one thread per (dst,rel) segment -> per-edge coef[h*E + pos].
// ---------------------------------------------------------------------------
__global__ __launch_bounds__(256) void seg_softmax(
    const int* __restrict__ rstart, const int* __restrict__ recs,
    const float* __restrict__ ai, const float* __restrict__ aj,
    float* __restrict__ coef) {
  int seg = blockIdx.x * blockDim.x + threadIdx.x;
  if (seg >= NK) return;
  int p0 = rstart[seg], p1 = rstart[seg + 1];
  if (p0 == p1) return;
  int d = seg / R_REL, r = seg - d * R_REL;
  float4 av = *reinterpret_cast<const float4*>(ai + ((long)r * N_NODES + d) * 4);
  float degf = (float)(rstart[(d + 1) * R_REL] - rstart[d * R_REL]);
  float m[4] = {-INFINITY, -INFINITY, -INFINITY, -INFINITY};
  float sum[4] = {0.f, 0.f, 0.f, 0.f};
  for (int p = p0; p < p1; ++p) {
    int s = recs[p] & 0xFFFF;
    float4 bv = *reinterpret_cast<const float4*>(aj + ((long)r * N_NODES + s) * 4);
    float al[4] = {lrelu(av.x + bv.x), lrelu(av.y + bv.y),
                   lrelu(av.z + bv.z), lrelu(av.w + bv.w)};
#pragma unroll
    for (int h = 0; h < 4; ++h) {
      float nm = fmaxf(m[h], al[h]);
      sum[h] = sum[h] * __expf(m[h] - nm) + __expf(al[h] - nm);
      m[h] = nm;
    }
  }
  float rs[4];
#pragma unroll
  for (int h = 0; h < 4; ++h) rs[h] = degf / (sum[h] + 1e-16f);
  for (int p = p0; p < p1; ++p) {
    int s = recs[p] & 0xFFFF;
    float4 bv = *reinterpret_cast<const float4*>(aj + ((long)r * N_NODES + s) * 4);
    float al[4] = {lrelu(av.x + bv.x), lrelu(av.y + bv.y),
                   lrelu(av.z + bv.z), lrelu(av.w + bv.w)};
#pragma unroll
    for (int h = 0; h < 4; ++h)
      coef[(long)h * E_EDGES + p] = __expf(al[h] - m[h]) * rs[h];
  }
}

// ---------------------------------------------------------------------------
// fused_agg: one wave per dst node; pure gather-accumulate over xwb.
// ---------------------------------------------------------------------------
__global__ __launch_bounds__(256) void fused_agg(
    const int* __restrict__ rstart, const int* __restrict__ recs,
    const float* __restrict__ coef, const ushort_t* __restrict__ xwb,
    ushort_t* __restrict__ xb_out, float* __restrict__ fout) {
  const int wave = threadIdx.x >> 6, lane = threadIdx.x & 63;
  const int d = blockIdx.x * 4 + wave;
  const int s0 = rstart[d * R_REL], s1 = rstart[(d + 1) * R_REL];
  const float* cfp = coef + (long)(lane >> 4) * E_EDGES;
  float acc0 = 0.f, acc1 = 0.f;
#pragma unroll 4
  for (int pos = s0; pos < s1; ++pos) {
    int rec = recs[pos];
    float cf = cfp[pos];
    int s = rec & 0xFFFF, r = rec >> 16;
    unsigned int pk = *reinterpret_cast<const unsigned int*>(
        xwb + (((long)r * N_NODES + s) << 7) + 2 * lane);
    acc0 += cf * b2f((ushort_t)(pk & 0xFFFF));
    acc1 += cf * b2f((ushort_t)(pk >> 16));
  }
  if (xb_out) {
    unsigned int po = ((unsigned int)f2b(acc1) << 16) | (unsigned int)f2b(acc0);
    *reinterpret_cast<unsigned int*>(xb_out + ((long)d << 7) + 2 * lane) = po;
  }
  if (fout) {
    *reinterpret_cast<float2*>(fout + ((long)d << 7) + 2 * lane) =
        make_float2(acc0, acc1);
  }
}

__global__ void final_linear(const float* __restrict__ x, const float* __restrict__ Wc,
                             const float* __restrict__ bc, float* __restrict__ out) {
  __shared__ float wcs[4 * 384];
  for (int t = threadIdx.x; t < 4 * 384; t += blockDim.x) wcs[t] = Wc[t];
  __syncthreads();
  int i = blockIdx.x * blockDim.x + threadIdx.x;
  if (i >= NPV) return;
  float acc[4] = {0.f, 0.f, 0.f, 0.f};
  for (int v = 0; v < 3; ++v) {
    const float* xr = x + ((long)v * NPV + i) * 128;
    for (int c = 0; c < 128; c += 4) {
      float4 xv = *reinterpret_cast<const float4*>(xr + c);
#pragma unroll
      for (int l = 0; l < 4; ++l) {
        const float* w = wcs + l * 384 + v * 128 + c;
        acc[l] += xv.x * w[0] + xv.y * w[1] + xv.z * w[2] + xv.w * w[3];
      }
    }
  }
#pragma unroll
  for (int l = 0; l < 4; ++l) out[(long)i * 4 + l] = acc[l] + bc[l];
}

// ---------------------------------------------------------------------------
static void run_layer(const ushort_t* xb_in, ushort_t* xb_out, float* fout,
                      const float* basis, const float* comp, const float* q,
                      const float* k, ushort_t* xwb, ushort_t* wTb, float* ai,
                      float* aj, float* coef, const int* rstart, const int* recs,
                      hipStream_t stream) {
  compute_wT_b<<<(R_REL * 128 * 128 + 255) / 256, 256, 0, stream>>>(comp, basis, wTb);
  mfma_gemm_nt<false, true><<<dim3(N_NODES / 64, 1, R_REL), 256, 0, stream>>>(
      xb_in, wTb, nullptr, xwb, 128, 128, 128 * 128, (long)N_NODES * 128,
      q, k, ai, aj);
  seg_softmax<<<(NK + 255) / 256, 256, 0, stream>>>(rstart, recs, ai, aj, coef);
  fused_agg<<<N_NODES / 4, 256, 0, stream>>>(rstart, recs, coef, xwb, xb_out, fout);
}

extern "C" void kernel_launch(void* const* d_in, const int* in_sizes, int n_in,
                              void* d_out, int out_size, void* d_ws, size_t ws_size,
                              hipStream_t stream) {
  const float* x0 = (const float*)d_in[0];
  const float* x1 = (const float*)d_in[1];
  const float* x2 = (const float*)d_in[2];
  const int* edge_index = (const int*)d_in[3];
  const int* edge_type = (const int*)d_in[4];
  const float* Wp0 = (const float*)d_in[5];
  const float* bp0 = (const float*)d_in[6];
  const float* Wp1 = (const float*)d_in[7];
  const float* bp1 = (const float*)d_in[8];
  const float* Wp2 = (const float*)d_in[9];
  const float* bp2 = (const float*)d_in[10];
  const float* basis0 = (const float*)d_in[11];
  const float* comp0 = (const float*)d_in[12];
  const float* q0 = (const float*)d_in[13];
  const float* k0 = (const float*)d_in[14];
  const float* basis1 = (const float*)d_in[15];
  const float* comp1 = (const float*)d_in[16];
  const float* q1 = (const float*)d_in[17];
  const float* k1 = (const float*)d_in[18];
  const float* Wc = (const float*)d_in[19];
  const float* bc = (const float*)d_in[20];

  const int* src = edge_index;
  const int* dst = edge_index + E_EDGES;

  // ---- workspace layout ----
  char* w = (char*)d_ws;
  auto alloc = [&](long bytes) {
    char* p = w;
    w += (bytes + 255) & ~255L;
    return p;
  };
  ushort_t* xbA  = (ushort_t*)alloc((long)NX * 2);
  ushort_t* xbB  = (ushort_t*)alloc((long)NX * 2);
  ushort_t* xwb  = (ushort_t*)alloc((long)R_REL * NX * 2);
  ushort_t* wTb  = (ushort_t*)alloc((long)R_REL * 128 * 128 * 2);
  ushort_t* padW = (ushort_t*)alloc(3L * 128 * WPAD * 2); // padded bf16 proj weights
  float* Cacc    = (float*)alloc((long)NX * 4);
  float* ai      = (float*)alloc((long)R_REL * N_NODES * 4 * 4);
  float* aj      = (float*)alloc((long)R_REL * N_NODES * 4 * 4);
  float* coef    = (float*)alloc((long)HEADS * E_EDGES * 4);
  int* cnt       = (int*)alloc((long)NK * 4);
  int* cursor    = (int*)alloc((long)NK * 4);
  int* rstart    = (int*)alloc((long)(NK + 1) * 4);
  int* recs      = (int*)alloc((long)E_EDGES * 4);
  int* blockSums = (int*)alloc((long)SCAN_BLOCKS * 4);

  // ---- projection weights -> padded bf16 (tiny; once)
  cvt_pad_bf16<<<128, 256, 0, stream>>>(Wp0, padW + 0L * 128 * WPAD, 128, 2000, WPAD);
  cvt_pad_bf16<<<128, 256, 0, stream>>>(Wp1, padW + 1L * 128 * WPAD, 128, 1500, WPAD);
  cvt_pad_bf16<<<128, 256, 0, stream>>>(Wp2, padW + 2L * 128 * WPAD, 128, 500, WPAD);

  // ---- projections: full-K per view, fused bias+relu+bf16 epilogue
  gemm_proj_full<<<dim3(NPV / 32, 3), 256, 0, stream>>>(
      x0, x1, x2, padW, bp0, bp1, bp2, xbA);

  // ---- CSR build keyed by (dst,rel) (once; shared by both layers)
  fill_f32<<<96, 256, 0, stream>>>((float*)cnt, 2L * NK, 0.f);  // cnt+cursor adjacent
  count_key<<<E_EDGES / 256, 256, 0, stream>>>(dst, edge_type, cnt, E_EDGES);
  scan_block<<<SCAN_BLOCKS, 256, 0, stream>>>(cnt, rstart, blockSums);
  scan_sums<<<1, SCAN_BLOCKS, 0, stream>>>(blockSums);
  add_offsets<<<SCAN_BLOCKS, 256, 0, stream>>>(rstart, blockSums);
  scatter_edges<<<E_EDGES / 256, 256, 0, stream>>>(src, dst, edge_type, rstart,
                                                   cursor, recs, E_EDGES);

  // ---- layer 0: xbA -> xbB (bf16)
  run_layer(xbA, xbB, nullptr, basis0, comp0, q0, k0, xwb, wTb, ai, aj, coef,
            rstart, recs, stream);
  // ---- layer 1: xbB -> Cacc (f32 only)
  run_layer(xbB, nullptr, Cacc, basis1, comp1, q1, k1, xwb, wTb, ai, aj, coef,
            rstart, recs, stream);

  final_linear<<<(NPV + 255) / 256, 256, 0, stream>>>(Cacc, Wc, bc, (float*)d_out);
}

// Round 19
// 268.821 us; speedup vs baseline: 1.0516x; 1.0260x over previous
//
#include <hip/hip_runtime.h>
#include <hip/hip_bf16.h>
#include <math.h>

#define N_NODES 24576
#define NPV 8192
#define E_EDGES 393216
#define R_REL 6
#define B_BASES 8
#define HEADS 4
#define NEG_SLOPE 0.2f
#define NX (N_NODES * 128)
#define NK (N_NODES * R_REL)
#define SCAN_BLOCKS (NK / 256)  // 576
#define WPAD 2048               // padded K stride for projection weights (bf16)

typedef unsigned short ushort_t;
using short8 = __attribute__((ext_vector_type(8))) short;
using f32x4 = __attribute__((ext_vector_type(4))) float;

__device__ __forceinline__ float lrelu(float x) { return x >= 0.f ? x : NEG_SLOPE * x; }
__device__ __forceinline__ float b2f(ushort_t u) {
  unsigned int v = ((unsigned int)u) << 16;
  float f;
  __builtin_memcpy(&f, &v, 4);
  return f;
}
__device__ __forceinline__ ushort_t f2b(float f) {
  __hip_bfloat16 h = __float2bfloat16(f);
  ushort_t u;
  __builtin_memcpy(&u, &h, 2);
  return u;
}

// ---------------------------------------------------------------------------
// cvt_pad3: all three proj weight matrices f32 -> padded bf16 in ONE launch.
// grid (128, 3); body identical to the proven cvt_pad_bf16.
// ---------------------------------------------------------------------------
__global__ void cvt_pad3_bf16(const float* __restrict__ w0,
                              const float* __restrict__ w1,
                              const float* __restrict__ w2,
                              ushort_t* __restrict__ outAll) {
  const int v = blockIdx.y;
  const float* in;
  int K;
  if (v == 0) { in = w0; K = 2000; }
  else if (v == 1) { in = w1; K = 1500; }
  else { in = w2; K = 500; }
  ushort_t* out = outAll + (long)v * 128 * WPAD;
  int kp8 = WPAD >> 3;
  int total = 128 * kp8;
  for (int t = blockIdx.x * blockDim.x + threadIdx.x; t < total;
       t += gridDim.x * blockDim.x) {
    int row = t / kp8;
    int c0 = (t - row * kp8) * 8;
    short8 o;
    if (c0 + 7 < K) {
      const float4 a = *reinterpret_cast<const float4*>(in + (long)row * K + c0);
      const float4 b = *reinterpret_cast<const float4*>(in + (long)row * K + c0 + 4);
      o[0] = (short)f2b(a.x); o[1] = (short)f2b(a.y);
      o[2] = (short)f2b(a.z); o[3] = (short)f2b(a.w);
      o[4] = (short)f2b(b.x); o[5] = (short)f2b(b.y);
      o[6] = (short)f2b(b.z); o[7] = (short)f2b(b.w);
    } else {
#pragma unroll
      for (int j = 0; j < 8; ++j) {
        int c = c0 + j;
        float vv = (c < K) ? in[(long)row * K + c] : 0.f;
        o[j] = (short)f2b(vv);
      }
    }
    *reinterpret_cast<short8*>(out + (long)row * WPAD + c0) = o;
  }
}

// ---------------------------------------------------------------------------
// gemm_proj_full (r17-proven): full K per view, fused bias+relu+bf16.
// ---------------------------------------------------------------------------
__global__ __launch_bounds__(256) void gemm_proj_full(
    const float* __restrict__ x0, const float* __restrict__ x1,
    const float* __restrict__ x2, const ushort_t* __restrict__ wb,
    const float* __restrict__ b0, const float* __restrict__ b1,
    const float* __restrict__ b2, ushort_t* __restrict__ xb) {
  __shared__ __align__(16) float Af[32 * 64];      // 8KB f32 A tile
  __shared__ __align__(16) ushort_t Ws[128 * 64];  // 16KB bf16 W tile
  const int z = blockIdx.y;
  const float* A;
  const ushort_t* W;
  const float* bias;
  int K;
  if (z == 0)      { A = x0; W = wb;                 bias = b0; K = 2000; }
  else if (z == 1) { A = x1; W = wb + 128L * WPAD;   bias = b1; K = 1500; }
  else             { A = x2; W = wb + 256L * WPAD;   bias = b2; K = 500; }
  const int nfull = K >> 6;
  const int tail = K & 63;
  const int nsteps = nfull + (tail ? 1 : 0);

  const int tid = threadIdx.x;
  const int wave = tid >> 6, lane = tid & 63;
  const int m0 = blockIdx.x * 32;
  const int wrow = (wave & 1) * 16;
  const int wcol = (wave >> 1) * 64;

  f32x4 acc[4];
#pragma unroll
  for (int n = 0; n < 4; ++n) acc[n] = (f32x4){0.f, 0.f, 0.f, 0.f};

  for (int step = 0; step < nsteps; ++step) {
    const int k0 = step << 6;
    __syncthreads();
    if (step < nfull) {
#pragma unroll
      for (int q = 0; q < 2; ++q) {
        int s = q * 256 + tid;
        int row = s >> 4, ch = s & 15;
        int sch = ch ^ (row & 15);
        const float* g = A + (long)(m0 + row) * K + k0 + sch * 4;
        __builtin_amdgcn_global_load_lds(
            (const __attribute__((address_space(1))) unsigned int*)g,
            (__attribute__((address_space(3))) unsigned int*)(Af + s * 4), 16, 0, 0);
      }
    } else {
#pragma unroll
      for (int q = 0; q < 2; ++q) {
        int s = q * 256 + tid;
        int row = s >> 4, ch = s & 15;
        int sch = ch ^ (row & 15);
        int gk = k0 + sch * 4;
        const float* gp = A + (long)(m0 + row) * K + gk;
        float4 v = make_float4(0.f, 0.f, 0.f, 0.f);
#pragma unroll
        for (int j = 0; j < 4; ++j)
          if (gk + j < K) (&v.x)[j] = gp[j];
        *reinterpret_cast<float4*>(Af + s * 4) = v;
      }
    }
#pragma unroll
    for (int q = 0; q < 4; ++q) {
      int s = q * 256 + tid;
      int row = s >> 3, ch = s & 7;
      int sch = ch ^ (row & 7);
      const ushort_t* g = W + (long)row * WPAD + k0 + sch * 8;
      __builtin_amdgcn_global_load_lds(
          (const __attribute__((address_space(1))) unsigned int*)g,
          (__attribute__((address_space(3))) unsigned int*)(Ws + s * 8), 16, 0, 0);
    }
    __syncthreads();
#pragma unroll
    for (int kk = 0; kk < 2; ++kk) {
      const int arow = wrow + (lane & 15);
      const int t = kk * 4 + (lane >> 4);
      const int sc0 = (2 * t) ^ (arow & 15);
      const int sc1 = (2 * t + 1) ^ (arow & 15);
      f32x4 a0 = *reinterpret_cast<const f32x4*>(Af + arow * 64 + sc0 * 4);
      f32x4 a1 = *reinterpret_cast<const f32x4*>(Af + arow * 64 + sc1 * 4);
      short8 afrag;
      afrag[0] = (short)f2b(a0[0]); afrag[1] = (short)f2b(a0[1]);
      afrag[2] = (short)f2b(a0[2]); afrag[3] = (short)f2b(a0[3]);
      afrag[4] = (short)f2b(a1[0]); afrag[5] = (short)f2b(a1[1]);
      afrag[6] = (short)f2b(a1[2]); afrag[7] = (short)f2b(a1[3]);
#pragma unroll
      for (int n = 0; n < 4; ++n) {
        const int brow = wcol + n * 16 + (lane & 15);
        const int bch = t ^ (brow & 7);
        short8 bfrag = *reinterpret_cast<const short8*>(Ws + brow * 64 + bch * 8);
        acc[n] = __builtin_amdgcn_mfma_f32_16x16x32_bf16(afrag, bfrag, acc[n], 0, 0, 0);
      }
    }
  }
  const int rbase = m0 + wrow + (lane >> 4) * 4;
  const int cb = lane & 15;
  ushort_t* out = xb + (long)z * NPV * 128;
#pragma unroll
  for (int n = 0; n < 4; ++n) {
    int col = wcol + n * 16 + cb;
    float bz = bias[col];
#pragma unroll
    for (int r = 0; r < 4; ++r) {
      float v = acc[n][r] + bz;
      v = v > 0.f ? v : 0.f;
      out[(long)(rbase + r) * 128 + col] = f2b(v);
    }
  }
}

// ---------------------------------------------------------------------------
// xw GEMM (r13/r17-proven): xwb[r][M,128] = bf16(xb @ w_r^T) + fused ai/aj.
// ---------------------------------------------------------------------------
template <bool SPLIT, bool TABLES>
__global__ __launch_bounds__(256) void mfma_gemm_nt(
    const ushort_t* __restrict__ A, const ushort_t* __restrict__ W,
    float* __restrict__ Cacc, ushort_t* __restrict__ Cb,
    int Kp, int kChunk, long strideW, long strideCz,
    const float* __restrict__ qt, const float* __restrict__ kt,
    float* __restrict__ ai, float* __restrict__ aj) {
  __shared__ __align__(16) ushort_t As[64 * 64];
  __shared__ __align__(16) ushort_t Ws[128 * 64];
  const int tid = threadIdx.x;
  const int wave = tid >> 6, lane = tid & 63;
  const int m0 = blockIdx.x * 64;
  const int kbase = blockIdx.y * kChunk;
  const ushort_t* Wz = W + (long)blockIdx.z * strideW;

  f32x4 acc[8];
#pragma unroll
  for (int n = 0; n < 8; ++n) acc[n] = (f32x4){0.f, 0.f, 0.f, 0.f};

  for (int k0 = kbase; k0 < kbase + kChunk; k0 += 64) {
    __syncthreads();
#pragma unroll
    for (int q = 0; q < 2; ++q) {
      int s = q * 256 + tid;
      int row = s >> 3, ch = s & 7;
      int sch = ch ^ (row & 7);
      const ushort_t* g = A + (long)(m0 + row) * Kp + k0 + sch * 8;
      __builtin_amdgcn_global_load_lds(
          (const __attribute__((address_space(1))) unsigned int*)g,
          (__attribute__((address_space(3))) unsigned int*)(As + s * 8), 16, 0, 0);
    }
#pragma unroll
    for (int q = 0; q < 4; ++q) {
      int s = q * 256 + tid;
      int row = s >> 3, ch = s & 7;
      int sch = ch ^ (row & 7);
      const ushort_t* g = Wz + (long)row * Kp + k0 + sch * 8;
      __builtin_amdgcn_global_load_lds(
          (const __attribute__((address_space(1))) unsigned int*)g,
          (__attribute__((address_space(3))) unsigned int*)(Ws + s * 8), 16, 0, 0);
    }
    __syncthreads();
#pragma unroll
    for (int kk = 0; kk < 2; ++kk) {
      const int arow = wave * 16 + (lane & 15);
      const int ach = (kk * 4 + (lane >> 4)) ^ (arow & 7);
      short8 afrag = *reinterpret_cast<const short8*>(As + arow * 64 + ach * 8);
#pragma unroll
      for (int n = 0; n < 8; ++n) {
        const int brow = n * 16 + (lane & 15);
        const int bch = (kk * 4 + (lane >> 4)) ^ (brow & 7);
        short8 bfrag = *reinterpret_cast<const short8*>(Ws + brow * 64 + bch * 8);
        acc[n] = __builtin_amdgcn_mfma_f32_16x16x32_bf16(afrag, bfrag, acc[n], 0, 0, 0);
      }
    }
  }
  const int rbase = m0 + wave * 16 + (lane >> 4) * 4;
  const int cb = lane & 15;
  if (SPLIT) {
#pragma unroll
    for (int n = 0; n < 8; ++n) {
      int col = n * 16 + cb;
#pragma unroll
      for (int r = 0; r < 4; ++r)
        atomicAdd(&Cacc[(long)(rbase + r) * 128 + col], acc[n][r]);
    }
  } else {
    ushort_t* Cz = Cb + (long)blockIdx.z * strideCz;
#pragma unroll
    for (int n = 0; n < 8; ++n) {
      int col = n * 16 + cb;
#pragma unroll
      for (int r = 0; r < 4; ++r)
        Cz[(long)(rbase + r) * 128 + col] = f2b(acc[n][r]);
    }
  }
  if (TABLES) {
    float aq[4][4], ak[4][4];
#pragma unroll
    for (int r = 0; r < 4; ++r)
#pragma unroll
      for (int h = 0; h < 4; ++h) { aq[r][h] = 0.f; ak[r][h] = 0.f; }
#pragma unroll
    for (int n = 0; n < 8; ++n) {
      int col = n * 16 + cb;
      float4 qv = *reinterpret_cast<const float4*>(qt + (long)col * 4);
      float4 kv = *reinterpret_cast<const float4*>(kt + (long)col * 4);
#pragma unroll
      for (int r = 0; r < 4; ++r) {
        float x = acc[n][r];
        aq[r][0] += x * qv.x; aq[r][1] += x * qv.y;
        aq[r][2] += x * qv.z; aq[r][3] += x * qv.w;
        ak[r][0] += x * kv.x; ak[r][1] += x * kv.y;
        ak[r][2] += x * kv.z; ak[r][3] += x * kv.w;
      }
    }
#pragma unroll
    for (int mk = 1; mk < 16; mk <<= 1) {
#pragma unroll
      for (int r = 0; r < 4; ++r)
#pragma unroll
        for (int h = 0; h < 4; ++h) {
          aq[r][h] += __shfl_xor(aq[r][h], mk);
          ak[r][h] += __shfl_xor(ak[r][h], mk);
        }
    }
    int rr = cb >> 2, hh = cb & 3;
    long row = (long)blockIdx.z * N_NODES + rbase + rr;
    ai[row * 4 + hh] = aq[rr][hh];
    aj[row * 4 + hh] = ak[rr][hh];
  }
}

// ---------------------------------------------------------------------------
__global__ void fill_f32(float* __restrict__ p, long n, float v) {
  long i = blockIdx.x * (long)blockDim.x + threadIdx.x;
  long stride = (long)gridDim.x * blockDim.x;
  for (; i < n; i += stride) p[i] = v;
}

// wTb[r,o,i] = bf16( sum_b comp[r,b] * basis[b,i,o] )
__global__ void compute_wT_b(const float* __restrict__ comp,
                             const float* __restrict__ basis,
                             ushort_t* __restrict__ wTb) {
  int idx = blockIdx.x * blockDim.x + threadIdx.x;
  if (idx >= R_REL * 128 * 128) return;
  int r = idx >> 14;
  int rem = idx & 16383;
  int o = rem >> 7;
  int i = rem & 127;
  float s = 0.f;
#pragma unroll
  for (int b = 0; b < B_BASES; ++b)
    s += comp[r * B_BASES + b] * basis[((b << 7) + i) * 128 + o];
  wTb[((long)(r << 7) + o) * 128 + i] = f2b(s);
}

// ---------------------------------------------------------------------------
// CSR build keyed by (dst*6 + rel): count -> hierarchical scan -> scatter.
// ---------------------------------------------------------------------------
__global__ void count_key(const int* __restrict__ dst, const int* __restrict__ et,
                          int* __restrict__ cnt, int E) {
  int e = blockIdx.x * blockDim.x + threadIdx.x;
  if (e < E) atomicAdd(&cnt[dst[e] * R_REL + et[e]], 1);
}

__global__ __launch_bounds__(256) void scan_block(const int* __restrict__ cnt,
                                                  int* __restrict__ start,
                                                  int* __restrict__ blockSums) {
  __shared__ int sm[256];
  const int t = threadIdx.x;
  const int i = blockIdx.x * 256 + t;
  int v = cnt[i];
  sm[t] = v;
  __syncthreads();
  for (int off = 1; off < 256; off <<= 1) {
    int u = (t >= off) ? sm[t - off] : 0;
    __syncthreads();
    sm[t] += u;
    __syncthreads();
  }
  start[i] = sm[t] - v;  // exclusive
  if (t == 255) blockSums[blockIdx.x] = sm[255];
}

__global__ __launch_bounds__(SCAN_BLOCKS) void scan_sums(int* __restrict__ blockSums) {
  __shared__ int sm[SCAN_BLOCKS];
  const int t = threadIdx.x;
  int v = blockSums[t];
  sm[t] = v;
  __syncthreads();
  for (int off = 1; off < SCAN_BLOCKS; off <<= 1) {
    int u = (t >= off) ? sm[t - off] : 0;
    __syncthreads();
    sm[t] += u;
    __syncthreads();
  }
  blockSums[t] = sm[t] - v;  // exclusive
}

__global__ __launch_bounds__(256) void add_offsets(int* __restrict__ start,
                                                   const int* __restrict__ blockSums) {
  int i = blockIdx.x * 256 + threadIdx.x;
  start[i] += blockSums[blockIdx.x];
  if (i == 0) start[NK] = E_EDGES;
}

__global__ void scatter_edges(const int* __restrict__ src, const int* __restrict__ dst,
                              const int* __restrict__ et, const int* __restrict__ start,
                              int* __restrict__ cursor, int* __restrict__ recs, int E) {
  int e = blockIdx.x * blockDim.x + threadIdx.x;
  if (e >= E) return;
  int key = dst[e] * R_REL + et[e];
  int pos = start[key] + atomicAdd(&cursor[key], 1);
  recs[pos] = src[e] | (et[e] << 16);
}

// ---------------------------------------------------------------------------
// seg_softmax: one thread per (dst,rel) segment -> per-edge coef[h*E + pos].
// ---------------------------------------------------------------------------
__global__ __launch_bounds__(256) void seg_softmax(
    const int* __restrict__ rstart, const int* __restrict__ recs,
    const float* __restrict__ ai, const float* __restrict__ aj,
    float* __restrict__ coef) {
  int seg = blockIdx.x * blockDim.x + threadIdx.x;
  if (seg >= NK) return;
  int p0 = rstart[seg], p1 = rstart[seg + 1];
  if (p0 == p1) return;
  int d = seg / R_REL, r = seg - d * R_REL;
  float4 av = *reinterpret_cast<const float4*>(ai + ((long)r * N_NODES + d) * 4);
  float degf = (float)(rstart[(d + 1) * R_REL] - rstart[d * R_REL]);
  float m[4] = {-INFINITY, -INFINITY, -INFINITY, -INFINITY};
  float sum[4] = {0.f, 0.f, 0.f, 0.f};
  for (int p = p0; p < p1; ++p) {
    int s = recs[p] & 0xFFFF;
    float4 bv = *reinterpret_cast<const float4*>(aj + ((long)r * N_NODES + s) * 4);
    float al[4] = {lrelu(av.x + bv.x), lrelu(av.y + bv.y),
                   lrelu(av.z + bv.z), lrelu(av.w + bv.w)};
#pragma unroll
    for (int h = 0; h < 4; ++h) {
      float nm = fmaxf(m[h], al[h]);
      sum[h] = sum[h] * __expf(m[h] - nm) + __expf(al[h] - nm);
      m[h] = nm;
    }
  }
  float rs[4];
#pragma unroll
  for (int h = 0; h < 4; ++h) rs[h] = degf / (sum[h] + 1e-16f);
  for (int p = p0; p < p1; ++p) {
    int s = recs[p] & 0xFFFF;
    float4 bv = *reinterpret_cast<const float4*>(aj + ((long)r * N_NODES + s) * 4);
    float al[4] = {lrelu(av.x + bv.x), lrelu(av.y + bv.y),
                   lrelu(av.z + bv.z), lrelu(av.w + bv.w)};
#pragma unroll
    for (int h = 0; h < 4; ++h)
      coef[(long)h * E_EDGES + p] = __expf(al[h] - m[h]) * rs[h];
  }
}

// ---------------------------------------------------------------------------
// fused_agg: one wave per dst node; pure gather-accumulate over xwb.
// ---------------------------------------------------------------------------
__global__ __launch_bounds__(256) void fused_agg(
    const int* __restrict__ rstart, const int* __restrict__ recs,
    const float* __restrict__ coef, const ushort_t* __restrict__ xwb,
    ushort_t* __restrict__ xb_out, float* __restrict__ fout) {
  const int wave = threadIdx.x >> 6, lane = threadIdx.x & 63;
  const int d = blockIdx.x * 4 + wave;
  const int s0 = rstart[d * R_REL], s1 = rstart[(d + 1) * R_REL];
  const float* cfp = coef + (long)(lane >> 4) * E_EDGES;
  float acc0 = 0.f, acc1 = 0.f;
#pragma unroll 4
  for (int pos = s0; pos < s1; ++pos) {
    int rec = recs[pos];
    float cf = cfp[pos];
    int s = rec & 0xFFFF, r = rec >> 16;
    unsigned int pk = *reinterpret_cast<const unsigned int*>(
        xwb + (((long)r * N_NODES + s) << 7) + 2 * lane);
    acc0 += cf * b2f((ushort_t)(pk & 0xFFFF));
    acc1 += cf * b2f((ushort_t)(pk >> 16));
  }
  if (xb_out) {
    unsigned int po = ((unsigned int)f2b(acc1) << 16) | (unsigned int)f2b(acc0);
    *reinterpret_cast<unsigned int*>(xb_out + ((long)d << 7) + 2 * lane) = po;
  }
  if (fout) {
    *reinterpret_cast<float2*>(fout + ((long)d << 7) + 2 * lane) =
        make_float2(acc0, acc1);
  }
}

__global__ void final_linear(const float* __restrict__ x, const float* __restrict__ Wc,
                             const float* __restrict__ bc, float* __restrict__ out) {
  __shared__ float wcs[4 * 384];
  for (int t = threadIdx.x; t < 4 * 384; t += blockDim.x) wcs[t] = Wc[t];
  __syncthreads();
  int i = blockIdx.x * blockDim.x + threadIdx.x;
  if (i >= NPV) return;
  float acc[4] = {0.f, 0.f, 0.f, 0.f};
  for (int v = 0; v < 3; ++v) {
    const float* xr = x + ((long)v * NPV + i) * 128;
    for (int c = 0; c < 128; c += 4) {
      float4 xv = *reinterpret_cast<const float4*>(xr + c);
#pragma unroll
      for (int l = 0; l < 4; ++l) {
        const float* w = wcs + l * 384 + v * 128 + c;
        acc[l] += xv.x * w[0] + xv.y * w[1] + xv.z * w[2] + xv.w * w[3];
      }
    }
  }
#pragma unroll
  for (int l = 0; l < 4; ++l) out[(long)i * 4 + l] = acc[l] + bc[l];
}

// ---------------------------------------------------------------------------
static void run_layer(const ushort_t* xb_in, ushort_t* xb_out, float* fout,
                      const float* basis, const float* comp, const float* q,
                      const float* k, ushort_t* xwb, ushort_t* wTb, float* ai,
                      float* aj, float* coef, const int* rstart, const int* recs,
                      hipStream_t stream) {
  compute_wT_b<<<(R_REL * 128 * 128 + 255) / 256, 256, 0, stream>>>(comp, basis, wTb);
  mfma_gemm_nt<false, true><<<dim3(N_NODES / 64, 1, R_REL), 256, 0, stream>>>(
      xb_in, wTb, nullptr, xwb, 128, 128, 128 * 128, (long)N_NODES * 128,
      q, k, ai, aj);
  seg_softmax<<<(NK + 255) / 256, 256, 0, stream>>>(rstart, recs, ai, aj, coef);
  fused_agg<<<N_NODES / 4, 256, 0, stream>>>(rstart, recs, coef, xwb, xb_out, fout);
}

extern "C" void kernel_launch(void* const* d_in, const int* in_sizes, int n_in,
                              void* d_out, int out_size, void* d_ws, size_t ws_size,
                              hipStream_t stream) {
  const float* x0 = (const float*)d_in[0];
  const float* x1 = (const float*)d_in[1];
  const float* x2 = (const float*)d_in[2];
  const int* edge_index = (const int*)d_in[3];
  const int* edge_type = (const int*)d_in[4];
  const float* Wp0 = (const float*)d_in[5];
  const float* bp0 = (const float*)d_in[6];
  const float* Wp1 = (const float*)d_in[7];
  const float* bp1 = (const float*)d_in[8];
  const float* Wp2 = (const float*)d_in[9];
  const float* bp2 = (const float*)d_in[10];
  const float* basis0 = (const float*)d_in[11];
  const float* comp0 = (const float*)d_in[12];
  const float* q0 = (const float*)d_in[13];
  const float* k0 = (const float*)d_in[14];
  const float* basis1 = (const float*)d_in[15];
  const float* comp1 = (const float*)d_in[16];
  const float* q1 = (const float*)d_in[17];
  const float* k1 = (const float*)d_in[18];
  const float* Wc = (const float*)d_in[19];
  const float* bc = (const float*)d_in[20];

  const int* src = edge_index;
  const int* dst = edge_index + E_EDGES;

  // ---- workspace layout ----
  char* w = (char*)d_ws;
  auto alloc = [&](long bytes) {
    char* p = w;
    w += (bytes + 255) & ~255L;
    return p;
  };
  ushort_t* xbA  = (ushort_t*)alloc((long)NX * 2);
  ushort_t* xbB  = (ushort_t*)alloc((long)NX * 2);
  ushort_t* xwb  = (ushort_t*)alloc((long)R_REL * NX * 2);
  ushort_t* wTb  = (ushort_t*)alloc((long)R_REL * 128 * 128 * 2);
  ushort_t* padW = (ushort_t*)alloc(3L * 128 * WPAD * 2); // padded bf16 proj weights
  float* Cacc    = (float*)alloc((long)NX * 4);
  float* ai      = (float*)alloc((long)R_REL * N_NODES * 4 * 4);
  float* aj      = (float*)alloc((long)R_REL * N_NODES * 4 * 4);
  float* coef    = (float*)alloc((long)HEADS * E_EDGES * 4);
  int* cnt       = (int*)alloc((long)NK * 4);
  int* cursor    = (int*)alloc((long)NK * 4);
  int* rstart    = (int*)alloc((long)(NK + 1) * 4);
  int* recs      = (int*)alloc((long)E_EDGES * 4);
  int* blockSums = (int*)alloc((long)SCAN_BLOCKS * 4);

  // ---- projection weights -> padded bf16 (one launch for all 3 views)
  cvt_pad3_bf16<<<dim3(128, 3), 256, 0, stream>>>(Wp0, Wp1, Wp2, padW);

  // ---- projections: full-K per view, fused bias+relu+bf16 epilogue
  gemm_proj_full<<<dim3(NPV / 32, 3), 256, 0, stream>>>(
      x0, x1, x2, padW, bp0, bp1, bp2, xbA);

  // ---- CSR build keyed by (dst,rel) (once; shared by both layers)
  fill_f32<<<96, 256, 0, stream>>>((float*)cnt, 2L * NK, 0.f);  // cnt+cursor adjacent
  count_key<<<E_EDGES / 256, 256, 0, stream>>>(dst, edge_type, cnt, E_EDGES);
  scan_block<<<SCAN_BLOCKS, 256, 0, stream>>>(cnt, rstart, blockSums);
  scan_sums<<<1, SCAN_BLOCKS, 0, stream>>>(blockSums);
  add_offsets<<<SCAN_BLOCKS, 256, 0, stream>>>(rstart, blockSums);
  scatter_edges<<<E_EDGES / 256, 256, 0, stream>>>(src, dst, edge_type, rstart,
                                                   cursor, recs, E_EDGES);

  // ---- layer 0: xbA -> xbB (bf16)
  run_layer(xbA, xbB, nullptr, basis0, comp0, q0, k0, xwb, wTb, ai, aj, coef,
            rstart, recs, stream);
  // ---- layer 1: xbB -> Cacc (f32 only)
  run_layer(xbB, nullptr, Cacc, basis1, comp1, q1, k1, xwb, wTb, ai, aj, coef,
            rstart, recs, stream);

  final_linear<<<(NPV + 255) / 256, 256, 0, stream>>>(Cacc, Wc, bc, (float*)d_out);
}